// Round 12
// baseline (983.922 us; speedup 1.0000x reference)
//
#include <hip/hip_runtime.h>
#include <math.h>

#define NN 8192      // nodes
#define NE 131072    // edges
#define ZK 288       // padded z width (258 -> 288, multiple of 32)
#define NG 64        // graphs
#define ASPLIT 16    // attention split-K (split = bid&15)
#define QB 512       // q-rows per attention block (16 waves x 32)
#define KB 32        // keys per attention chunk

typedef __attribute__((ext_vector_type(8))) short bf16x8;
typedef __attribute__((ext_vector_type(4))) float f32x4;
typedef __attribute__((ext_vector_type(8))) _Float16 f16x8;
typedef __attribute__((ext_vector_type(4))) _Float16 f16x4;

static __device__ __forceinline__ unsigned short f2bf(float f) {
    unsigned u = __float_as_uint(f);
    unsigned r = (u + 0x7FFFu + ((u >> 16) & 1u)) >> 16;   // RNE
    return (unsigned short)r;
}
static __device__ __forceinline__ float b2f(unsigned short h) {
    return __uint_as_float(((unsigned)h) << 16);
}

// ------------------------- counts via per-block LDS histograms (G12)
__global__ __launch_bounds__(256) void k_counts(const int* __restrict__ ei,
    const int* __restrict__ batch, int* ncnt, int* ecnt, int* indeg)
{
    __shared__ int he[NG], hn[NG];
    const int t = threadIdx.x, b = blockIdx.x;
    if (t < NG) { he[t] = 0; hn[t] = 0; }
    __syncthreads();
    const int e0 = b * (NE / 64);
#pragma unroll
    for (int i = 0; i < (NE / 64) / 256; ++i) {
        int idx = e0 + i * 256 + t;
        int src = ei[idx], dst = ei[NE + idx];
        atomicAdd(&he[batch[src]], 1);
        atomicAdd(&indeg[dst], 1);
    }
    if (t < 128) atomicAdd(&hn[batch[b * 128 + t]], 1);
    __syncthreads();
    if (t < NG) {
        if (he[t]) atomicAdd(&ecnt[t], he[t]);
        if (hn[t]) atomicAdd(&ncnt[t], hn[t]);
    }
}

// -------- encoder + size feats -> zh/zl (split-fp16, ZK) and zb (bf16, 256)
__global__ __launch_bounds__(256) void k_encoder(const float* __restrict__ x,
    const float* __restrict__ encW, const float* __restrict__ encb,
    const int* __restrict__ batch, const int* __restrict__ ncnt,
    const int* __restrict__ ecnt, _Float16* __restrict__ zh,
    _Float16* __restrict__ zl, unsigned short* __restrict__ zb)
{
    int n = blockIdx.x, c = threadIdx.x;
    __shared__ float xr[8];
    if (c < 6) xr[c] = x[n * 6 + c];
    __syncthreads();
    float a = encb[c];
#pragma unroll
    for (int i = 0; i < 6; ++i) a = fmaf(xr[i], encW[i * 256 + c], a);
    float h = fmaxf(a, 0.f);
    _Float16 hi = (_Float16)h;
    zh[(size_t)n * ZK + c] = hi;
    zl[(size_t)n * ZK + c] = (_Float16)(h - (float)hi);
    zb[n * 256 + c] = f2bf(h);
    if (c == 0) {
        int g = batch[n];
        float s0 = log1pf((float)ncnt[g]);
        float s1 = log1pf((float)ecnt[g]);
        _Float16 h0 = (_Float16)s0, h1 = (_Float16)s1;
        zh[(size_t)n * ZK + 256] = h0;
        zl[(size_t)n * ZK + 256] = (_Float16)(s0 - (float)h0);
        zh[(size_t)n * ZK + 257] = h1;
        zl[(size_t)n * ZK + 257] = (_Float16)(s1 - (float)h1);
    }
    if (c >= 2 && c < 32) {                       // zero pad 258..287
        zh[(size_t)n * ZK + 256 + c] = (_Float16)0.f;
        zl[(size_t)n * ZK + 256 + c] = (_Float16)0.f;
    }
}

// ---------------------------------------------------------------- CSR build
__global__ __launch_bounds__(256) void k_scan(const int* __restrict__ indeg,
                                              int* __restrict__ rowptr)
{
    __shared__ int part[256];
    int t = threadIdx.x;
    int base = t * 32, s = 0;
    for (int i = 0; i < 32; ++i) s += indeg[base + i];
    part[t] = s;
    __syncthreads();
    if (t == 0) {
        int run = 0;
        for (int i = 0; i < 256; ++i) { int v = part[i]; part[i] = run; run += v; }
        rowptr[NN] = run;
    }
    __syncthreads();
    int run = part[t];
    for (int i = 0; i < 32; ++i) { rowptr[base + i] = run; run += indeg[base + i]; }
}

__global__ __launch_bounds__(256) void k_fill(const int* __restrict__ ei,
    const int* __restrict__ rowptr, int* __restrict__ cursor, int* __restrict__ colidx)
{
    int tid = blockIdx.x * 256 + threadIdx.x;
    if (tid >= NE) return;
    int dst = ei[NE + tid];
    int pos = atomicAdd(&cursor[dst], 1);
    colidx[rowptr[dst] + pos] = ei[tid];
}

// ---------------- Wq/Wk -> split-fp16, transposed [sel][out=256][in=288]
__global__ __launch_bounds__(256) void k_prep_qkw(const float* __restrict__ qW,
    const float* __restrict__ kW, _Float16* __restrict__ Wth,
    _Float16* __restrict__ Wtl)
{
    int idx = blockIdx.x * 256 + threadIdx.x;     // 2*256*288 = 147456
    int r = idx % ZK;
    int c = (idx / ZK) & 255;
    int sel = idx / (ZK * 256);
    const float* W = sel ? kW : qW;
    float w = (r < 258) ? W[r * 256 + c] : 0.f;
    _Float16 hi = (_Float16)w;
    Wth[idx] = hi;
    Wtl[idx] = (_Float16)(w - (float)hi);
}

// W_vo = v_W @ out_W (padded to ZK rows), bvo = v_b @ out_W
__global__ __launch_bounds__(256) void k_prep_vo(const float* __restrict__ vW,
    const float* __restrict__ vb, const float* __restrict__ outW,
    float* __restrict__ Wvo, float* __restrict__ bvo)
{
    int idx = blockIdx.x * 256 + threadIdx.x;
    if (idx < ZK * 8) {
        int r = idx >> 3, e = idx & 7;
        float s = 0.f;
        if (r < 258)
            for (int c = 0; c < 256; ++c) s = fmaf(vW[r * 256 + c], outW[c * 8 + e], s);
        Wvo[idx] = s;
    } else if (idx < ZK * 8 + 8) {
        int e = idx - ZK * 8;
        float s = 0.f;
        for (int c = 0; c < 256; ++c) s = fmaf(vb[c], outW[c * 8 + e], s);
        bvo[e] = s;
    }
}

// expert weights -> bf16, transposed to [out][in] so B-frags load contiguous
__global__ __launch_bounds__(256) void k_prep_w(const float* __restrict__ eWh,
    const float* __restrict__ eWo, unsigned short* __restrict__ Bth,
    unsigned short* __restrict__ Bto)
{
    int id = blockIdx.x * 256 + threadIdx.x;
    if (id < 16 * 65536) {
        int h = id & 255, kcol = (id >> 8) & 255, m = id >> 16;  // m = e*2+l
        Bth[id] = f2bf(eWh[((size_t)m * 256 + h) * 256 + kcol]);
    } else if (id < 24 * 65536) {
        int j = id - 16 * 65536;
        int h = j & 255, o = (j >> 8) & 255, e = j >> 16;
        Bto[j] = f2bf(eWo[((size_t)e * 256 + h) * 256 + o]);
    }
}

// -------- split-fp16 MFMA GEMM for q/k: C = (z @ W + bias) * scl -> (hi,lo)
// 128x128 tile, 512 thr (8 waves 2x4), K=288 in 9 steps of 32.
// acc = Ah*Bh + Ah*Bl + Al*Bh (fp32 MFMA accum).
// 1-D grid: sel = bid&1 (q/k), tile = bid>>1 (2 n-tiles x 64 m-tiles).
__global__ __launch_bounds__(512) void k_gemm_qk(
    const _Float16* __restrict__ zh, const _Float16* __restrict__ zl,
    const _Float16* __restrict__ Wth, const _Float16* __restrict__ Wtl,
    const float* __restrict__ qb, const float* __restrict__ kb,
    _Float16* __restrict__ qho, _Float16* __restrict__ qlo,
    _Float16* __restrict__ kho, _Float16* __restrict__ klo, float scale)
{
    const int bid = blockIdx.x;
    const int sel = bid & 1;
    const int tile = bid >> 1;
    const int n0 = (tile & 1) * 128, m0 = (tile >> 1) * 128;
    const _Float16* Bh = Wth + (size_t)sel * 256 * ZK;
    const _Float16* Bl = Wtl + (size_t)sel * 256 * ZK;
    const float* bias = sel ? kb : qb;
    _Float16* Ch = sel ? kho : qho;
    _Float16* Cl = sel ? klo : qlo;
    const float scl = sel ? 1.0f : scale;
    __shared__ _Float16 Ash[128][40], Asl[128][40];
    __shared__ _Float16 Bsh[128][40], Bsl[128][40];
    const int t = threadIdx.x;
    const int wid = t >> 6, lane = t & 63;
    const int wr = wid >> 2, wc = wid & 3;
    const int lr = lane & 15, lg = lane >> 4;
    f32x4 acc[4][2];
#pragma unroll
    for (int mf = 0; mf < 4; ++mf)
#pragma unroll
        for (int nf = 0; nf < 2; ++nf) acc[mf][nf] = (f32x4){0.f, 0.f, 0.f, 0.f};

    const int rA = t >> 2, cA = t & 3;
    for (int k0 = 0; k0 < ZK; k0 += 32) {
        *(uint4*)&Ash[rA][8 * cA] = *(const uint4*)&zh[(size_t)(m0 + rA) * ZK + k0 + 8 * cA];
        *(uint4*)&Asl[rA][8 * cA] = *(const uint4*)&zl[(size_t)(m0 + rA) * ZK + k0 + 8 * cA];
        *(uint4*)&Bsh[rA][8 * cA] = *(const uint4*)&Bh[(size_t)(n0 + rA) * ZK + k0 + 8 * cA];
        *(uint4*)&Bsl[rA][8 * cA] = *(const uint4*)&Bl[(size_t)(n0 + rA) * ZK + k0 + 8 * cA];
        __syncthreads();
        f16x8 ah[4], al[4], bh[2], bl[2];
#pragma unroll
        for (int mf = 0; mf < 4; ++mf) {
            ah[mf] = *(const f16x8*)&Ash[wr * 64 + mf * 16 + lr][8 * lg];
            al[mf] = *(const f16x8*)&Asl[wr * 64 + mf * 16 + lr][8 * lg];
        }
#pragma unroll
        for (int nf = 0; nf < 2; ++nf) {
            bh[nf] = *(const f16x8*)&Bsh[wc * 32 + nf * 16 + lr][8 * lg];
            bl[nf] = *(const f16x8*)&Bsl[wc * 32 + nf * 16 + lr][8 * lg];
        }
#pragma unroll
        for (int mf = 0; mf < 4; ++mf)
#pragma unroll
            for (int nf = 0; nf < 2; ++nf) {
                acc[mf][nf] = __builtin_amdgcn_mfma_f32_16x16x32_f16(ah[mf], bh[nf], acc[mf][nf], 0, 0, 0);
                acc[mf][nf] = __builtin_amdgcn_mfma_f32_16x16x32_f16(ah[mf], bl[nf], acc[mf][nf], 0, 0, 0);
                acc[mf][nf] = __builtin_amdgcn_mfma_f32_16x16x32_f16(al[mf], bh[nf], acc[mf][nf], 0, 0, 0);
            }
        __syncthreads();
    }
#pragma unroll
    for (int mf = 0; mf < 4; ++mf)
#pragma unroll
        for (int reg = 0; reg < 4; ++reg) {
            int m = m0 + wr * 64 + mf * 16 + lg * 4 + reg;
#pragma unroll
            for (int nf = 0; nf < 2; ++nf) {
                int c = n0 + wc * 32 + nf * 16 + lr;
                float v = (acc[mf][nf][reg] + bias[c]) * scl;
                _Float16 hi = (_Float16)v;
                Ch[(size_t)m * 256 + c] = hi;
                Cl[(size_t)m * 256 + c] = (_Float16)(v - (float)hi);
            }
        }
}

// ----------------------------------------------------- bf16 MFMA GEMM
// 128x128 tile, 512 thr (8 waves as 2x4), BK=32, 16x16x32 MFMA.
// 1-D grid: expert = bid&7 (XCD-pinned), tile = bid>>3 (2 n-tiles, 64 m-tiles)
// mode 0: relu -> bf16 Cb.  mode 1: Ys[slot] = w*(acc+bias) (top-2 slots).
__global__ __launch_bounds__(512) void k_gemm_bf(
    const unsigned short* __restrict__ A,
    const unsigned short* __restrict__ Bt,
    const float* __restrict__ bias,
    unsigned short* __restrict__ Cb,
    float* __restrict__ Ys,
    const float* __restrict__ sparse,
    const int* __restrict__ i1,
    long long aStrideZ, long long btStrideZ, long long cStrideZ, int biasStrideZ,
    int mode)
{
    const int bid = blockIdx.x;
    const int ez = bid & 7;
    const int tile = bid >> 3;
    const int n0 = (tile & 1) * 128, m0 = (tile >> 1) * 128;
    A    += (size_t)ez * aStrideZ;
    Bt   += (size_t)ez * btStrideZ;
    bias += (size_t)ez * biasStrideZ;
    if (mode == 0) Cb += (size_t)ez * cStrideZ;
    __shared__ unsigned short As[128][40];
    __shared__ unsigned short Bs[128][40];
    const int t = threadIdx.x;
    const int wid = t >> 6, lane = t & 63;
    const int wr = wid >> 2, wc = wid & 3;       // 2x4 waves: 64x32 per wave
    const int lr = lane & 15, lg = lane >> 4;
    f32x4 acc[4][2];
#pragma unroll
    for (int mf = 0; mf < 4; ++mf)
#pragma unroll
        for (int nf = 0; nf < 2; ++nf) acc[mf][nf] = (f32x4){0.f, 0.f, 0.f, 0.f};

    const int rA = t >> 2, cA = t & 3;           // 128 rows x 4 col-chunks
    for (int k0 = 0; k0 < 256; k0 += 32) {
        uint4 va = *(const uint4*)&A[(size_t)(m0 + rA) * 256 + k0 + 8 * cA];
        uint4 vB = *(const uint4*)&Bt[(size_t)(n0 + rA) * 256 + k0 + 8 * cA];
        *(uint4*)&As[rA][8 * cA] = va;
        *(uint4*)&Bs[rA][8 * cA] = vB;
        __syncthreads();
        bf16x8 a[4], b[2];
#pragma unroll
        for (int mf = 0; mf < 4; ++mf)
            a[mf] = *(const bf16x8*)&As[wr * 64 + mf * 16 + lr][8 * lg];
#pragma unroll
        for (int nf = 0; nf < 2; ++nf)
            b[nf] = *(const bf16x8*)&Bs[wc * 32 + nf * 16 + lr][8 * lg];
#pragma unroll
        for (int mf = 0; mf < 4; ++mf)
#pragma unroll
            for (int nf = 0; nf < 2; ++nf)
                acc[mf][nf] = __builtin_amdgcn_mfma_f32_16x16x32_bf16(
                    a[mf], b[nf], acc[mf][nf], 0, 0, 0);
        __syncthreads();
    }
    if (mode == 0) {
#pragma unroll
        for (int mf = 0; mf < 4; ++mf)
#pragma unroll
            for (int reg = 0; reg < 4; ++reg) {
                int m = m0 + wr * 64 + mf * 16 + lg * 4 + reg;
#pragma unroll
                for (int nf = 0; nf < 2; ++nf) {
                    int c = n0 + wc * 32 + nf * 16 + lr;
                    float v = acc[mf][nf][reg] + bias[c];
                    Cb[(size_t)m * 256 + c] = f2bf(fmaxf(v, 0.f));
                }
            }
    } else {
#pragma unroll
        for (int mf = 0; mf < 4; ++mf)
#pragma unroll
            for (int reg = 0; reg < 4; ++reg) {
                int m = m0 + wr * 64 + mf * 16 + lg * 4 + reg;
                float w = sparse[m * 8 + ez];
                if (w != 0.f) {
                    int slot = (ez == i1[m]) ? 0 : 1;
                    float* dst = Ys + (size_t)slot * NN * 256 + (size_t)m * 256;
#pragma unroll
                    for (int nf = 0; nf < 2; ++nf) {
                        int c = n0 + wc * 32 + nf * 16 + lr;
                        dst[c] = w * (acc[mf][nf][reg] + bias[c]);
                    }
                }
            }
    }
}

// ------------------------------------------------------------- vo = z @ Wvo
__global__ __launch_bounds__(256) void k_vo(const _Float16* __restrict__ zh,
    const _Float16* __restrict__ zl, const float* __restrict__ Wvo,
    const float* __restrict__ bvo, float* __restrict__ vo)
{
    int n = blockIdx.x * 4 + (threadIdx.x >> 6);
    int lane = threadIdx.x & 63;
    float p[8];
#pragma unroll
    for (int e = 0; e < 8; ++e) p[e] = 0.f;
    for (int kk = lane; kk < ZK; kk += 64) {
        float zv = (float)zh[(size_t)n * ZK + kk] + (float)zl[(size_t)n * ZK + kk];
        float4 w0 = *(const float4*)&Wvo[kk * 8];
        float4 w1 = *(const float4*)&Wvo[kk * 8 + 4];
        p[0] = fmaf(zv, w0.x, p[0]); p[1] = fmaf(zv, w0.y, p[1]);
        p[2] = fmaf(zv, w0.z, p[2]); p[3] = fmaf(zv, w0.w, p[3]);
        p[4] = fmaf(zv, w1.x, p[4]); p[5] = fmaf(zv, w1.y, p[5]);
        p[6] = fmaf(zv, w1.z, p[6]); p[7] = fmaf(zv, w1.w, p[7]);
    }
#pragma unroll
    for (int msk = 1; msk <= 32; msk <<= 1)
#pragma unroll
        for (int e = 0; e < 8; ++e) p[e] += __shfl_xor(p[e], msk);
    if (lane == 0) {
#pragma unroll
        for (int e = 0; e < 8; ++e) vo[n * 8 + e] = p[e] + bvo[e];
    }
}

// ------------------- split-fp16 MFMA flash attention, swapped operands
// 1024 threads = 16 waves = 4 waves/SIMD BY CONSTRUCTION (R11 lesson: the
// 2-block-per-CU scheme never co-scheduled; occupancy stuck at 1 block/CU,
// pipes serialized). Per-wave code identical to R11 (32 rows/wave, 128 VGPR
// Q frags); QB=512; grid 16 rowblocks x 16 splits = 256 blocks = 1/CU.
// K staged via global_load_lds width=16; LDS linear, swizzle on the global
// source (rule #21).
__global__ __launch_bounds__(1024, 2) void k_attn_mfma(
    const _Float16* __restrict__ qh_, const _Float16* __restrict__ ql_,
    const _Float16* __restrict__ kh, const _Float16* __restrict__ kl,
    const float* __restrict__ vo, float* __restrict__ pm,
    float* __restrict__ pl, float* __restrict__ pacc)
{
    __shared__ uint4 lds[2][KB * 64];   // per key: 512B hi | 512B lo (16B units)
    const int bid = blockIdx.x;
    const int split = bid & 15;
    const int rowblk = bid >> 4;
    const int n0 = rowblk * QB;
    const int t = threadIdx.x, w = t >> 6, lane = t & 63;
    const int g = lane >> 4, c = lane & 15;

    // Q B-fragments (col=lane&15=row, k=8*g + st*32), persistent in registers
    f16x8 bqh[2][8], bql[2][8];
#pragma unroll
    for (int rs = 0; rs < 2; ++rs) {
        const int row = n0 + w * 32 + rs * 16 + c;
#pragma unroll
        for (int st = 0; st < 8; ++st) {
            bqh[rs][st] = *(const f16x8*)&qh_[(size_t)row * 256 + st * 32 + g * 8];
            bql[rs][st] = *(const f16x8*)&ql_[(size_t)row * 256 + st * 32 + g * 8];
        }
    }
    float m_[2] = {-INFINITY, -INFINITY};
    float l_[2] = {0.f, 0.f};
    float pv[2][8];
#pragma unroll
    for (int rs = 0; rs < 2; ++rs)
#pragma unroll
        for (int e = 0; e < 8; ++e) pv[rs][e] = 0.f;

    const int kbase0 = split * (NN / ASPLIT);
    // Direct global->LDS staging. Linear LDS unit u = i*1024 + t holds the
    // swizzled source chunk: key=u>>6, half=(u>>5)&1, c16=(u&31)^(key&7).
    auto STAGE = [&](int buf, int kb) {
#pragma unroll
        for (int i = 0; i < 2; ++i) {
            int u = i * 1024 + t;
            int key = u >> 6;
            int half = (u >> 5) & 1;
            int c16 = (u & 31) ^ (key & 7);      // pre-swizzled source
            const _Float16* src = half ? kl : kh;
            const _Float16* gp = src + (size_t)(kb + key) * 256 + c16 * 8;
            uint4* lp = &lds[buf][i * 1024 + (t & ~63)];  // wave-uniform base
            __builtin_amdgcn_global_load_lds(
                (const __attribute__((address_space(1))) void*)gp,
                (__attribute__((address_space(3))) void*)lp, 16, 0, 0);
        }
    };
    STAGE(0, kbase0);
    __syncthreads();
    int cur = 0;
    const int NCH = (NN / ASPLIT) / KB;   // 16 chunks
    for (int ch = 0; ch < NCH; ++ch) {
        const int kbase = kbase0 + ch * KB;
        if (ch + 1 < NCH) STAGE(cur ^ 1, kbase + KB);   // async; rides vmcnt
#pragma unroll
        for (int kt = 0; kt < 2; ++kt) {
            const char* kbp = (const char*)lds[cur] + (kt * 16 + c) * 1024;
            const int swz = ((kt * 16 + c) & 7) << 4;
            f32x4 acc0 = (f32x4){0.f, 0.f, 0.f, 0.f};
            f32x4 acc1 = (f32x4){0.f, 0.f, 0.f, 0.f};
            __builtin_amdgcn_s_setprio(1);
#pragma unroll
            for (int st = 0; st < 8; ++st) {
                const int off = (st * 64 + g * 16) ^ swz;
                f16x8 kah = *(const f16x8*)(kbp + off);
                f16x8 kal = *(const f16x8*)(kbp + 512 + off);
                acc0 = __builtin_amdgcn_mfma_f32_16x16x32_f16(kah, bqh[0][st], acc0, 0, 0, 0);
                acc0 = __builtin_amdgcn_mfma_f32_16x16x32_f16(kal, bqh[0][st], acc0, 0, 0, 0);
                acc0 = __builtin_amdgcn_mfma_f32_16x16x32_f16(kah, bql[0][st], acc0, 0, 0, 0);
                acc1 = __builtin_amdgcn_mfma_f32_16x16x32_f16(kah, bqh[1][st], acc1, 0, 0, 0);
                acc1 = __builtin_amdgcn_mfma_f32_16x16x32_f16(kal, bqh[1][st], acc1, 0, 0, 0);
                acc1 = __builtin_amdgcn_mfma_f32_16x16x32_f16(kah, bql[1][st], acc1, 0, 0, 0);
            }
            __builtin_amdgcn_s_setprio(0);
            const int kb2 = kbase + kt * 16 + 4 * g;
            float4 w0[4], w1[4];
#pragma unroll
            for (int r = 0; r < 4; ++r) {
                w0[r] = *(const float4*)&vo[(kb2 + r) * 8];
                w1[r] = *(const float4*)&vo[(kb2 + r) * 8 + 4];
            }
#pragma unroll
            for (int rs = 0; rs < 2; ++rs) {
                f32x4 s = rs ? acc1 : acc0;
                float cm = fmaxf(fmaxf(s[0], s[1]), fmaxf(s[2], s[3]));
                float mn = fmaxf(m_[rs], cm);
                float rsc = __expf(m_[rs] - mn);
                float p0 = __expf(s[0] - mn);
                float p1 = __expf(s[1] - mn);
                float p2 = __expf(s[2] - mn);
                float p3 = __expf(s[3] - mn);
                l_[rs] = l_[rs] * rsc + (p0 + p1 + p2 + p3);
                m_[rs] = mn;
                pv[rs][0] = pv[rs][0]*rsc + p0*w0[0].x + p1*w0[1].x + p2*w0[2].x + p3*w0[3].x;
                pv[rs][1] = pv[rs][1]*rsc + p0*w0[0].y + p1*w0[1].y + p2*w0[2].y + p3*w0[3].y;
                pv[rs][2] = pv[rs][2]*rsc + p0*w0[0].z + p1*w0[1].z + p2*w0[2].z + p3*w0[3].z;
                pv[rs][3] = pv[rs][3]*rsc + p0*w0[0].w + p1*w0[1].w + p2*w0[2].w + p3*w0[3].w;
                pv[rs][4] = pv[rs][4]*rsc + p0*w1[0].x + p1*w1[1].x + p2*w1[2].x + p3*w1[3].x;
                pv[rs][5] = pv[rs][5]*rsc + p0*w1[0].y + p1*w1[1].y + p2*w1[2].y + p3*w1[3].y;
                pv[rs][6] = pv[rs][6]*rsc + p0*w1[0].z + p1*w1[1].z + p2*w1[2].z + p3*w1[3].z;
                pv[rs][7] = pv[rs][7]*rsc + p0*w1[0].w + p1*w1[1].w + p2*w1[2].w + p3*w1[3].w;
            }
        }
        __syncthreads();
        cur ^= 1;
    }
    // --- merge across the 4 lanes (g=0..3) sharing each q-row ---
#pragma unroll
    for (int msk = 16; msk <= 32; msk <<= 1) {
#pragma unroll
        for (int rs = 0; rs < 2; ++rs) {
            float mo = __shfl_xor(m_[rs], msk);
            float lo = __shfl_xor(l_[rs], msk);
            float mn = fmaxf(m_[rs], mo);
            float a = __expf(m_[rs] - mn), b = __expf(mo - mn);
            l_[rs] = l_[rs] * a + lo * b;
#pragma unroll
            for (int e = 0; e < 8; ++e) {
                float po = __shfl_xor(pv[rs][e], msk);
                pv[rs][e] = pv[rs][e] * a + po * b;
            }
            m_[rs] = mn;
        }
    }
    if (g == 0) {
#pragma unroll
        for (int rs = 0; rs < 2; ++rs) {
            int n = n0 + w * 32 + rs * 16 + c;
            pm[split * NN + n] = m_[rs];
            pl[split * NN + n] = l_[rs];
#pragma unroll
            for (int e = 0; e < 8; ++e)
                pacc[(size_t)split * NN * 8 + n * 8 + e] = pv[rs][e];
        }
    }
}

// ----------------------------------- merge split-K partials -> top2 weights
__global__ __launch_bounds__(256) void k_attn_merge(
    const float* __restrict__ pm, const float* __restrict__ pl,
    const float* __restrict__ pacc, const float* __restrict__ outb,
    float* __restrict__ sparse, int* __restrict__ i1o)
{
    int n = blockIdx.x * 256 + threadIdx.x;
    float mn = -INFINITY;
#pragma unroll
    for (int s = 0; s < ASPLIT; ++s) mn = fmaxf(mn, pm[s * NN + n]);
    float l = 0.f;
    float lg[8];
#pragma unroll
    for (int e = 0; e < 8; ++e) lg[e] = 0.f;
#pragma unroll
    for (int s = 0; s < ASPLIT; ++s) {
        float r = __expf(pm[s * NN + n] - mn);
        l += pl[s * NN + n] * r;
#pragma unroll
        for (int e = 0; e < 8; ++e)
            lg[e] += pacc[(size_t)s * NN * 8 + n * 8 + e] * r;
    }
    float inv = 1.f / l;
#pragma unroll
    for (int e = 0; e < 8; ++e) lg[e] = lg[e] * inv + outb[e];
    int i1 = 0; float v1 = lg[0];
#pragma unroll
    for (int e = 1; e < 8; ++e) if (lg[e] > v1) { v1 = lg[e]; i1 = e; }
    int i2 = -1; float v2 = -INFINITY;
#pragma unroll
    for (int e = 0; e < 8; ++e) if (e != i1 && lg[e] > v2) { v2 = lg[e]; i2 = e; }
    float e2 = __expf(v2 - v1);
    float w1 = 1.f / (1.f + e2);
    float w2 = e2 / (1.f + e2);
#pragma unroll
    for (int e = 0; e < 8; ++e)
        sparse[n * 8 + e] = (e == i1) ? w1 : ((e == i2) ? w2 : 0.f);
    i1o[n] = i1;
}

// ------------------- bf16 gather-mean: X = bf16(src + neigh_mean(src))
// 1-D grid: expert = bid & ((1<<eshift)-1) (XCD-pinned), node-blk = bid>>eshift
// 4-way unrolled gather: 4 row-loads in flight, 4 independent accumulators.
__global__ __launch_bounds__(256) void k_agg_b2b(
    const unsigned short* __restrict__ HeAll, const int* __restrict__ rowptr,
    const int* __restrict__ colidx, unsigned short* __restrict__ XAll,
    int eshift)
{
    const int bid = blockIdx.x;
    const int e = bid & ((1 << eshift) - 1);
    const int nb = bid >> eshift;
    const unsigned short* He = HeAll + (size_t)e * NN * 256;
    unsigned short* X = XAll + (size_t)e * NN * 256;
    int n = nb * 4 + (threadIdx.x >> 6);
    int c4 = (threadIdx.x & 63) * 4;
    int r0 = rowptr[n], r1 = rowptr[n + 1];
    float a0 = 0.f, a1 = 0.f, a2 = 0.f, a3 = 0.f;
    float b0 = 0.f, b1 = 0.f, b2 = 0.f, b3 = 0.f;
    float e0 = 0.f, e1 = 0.f, e2 = 0.f, e3 = 0.f;
    float d0 = 0.f, d1 = 0.f, d2 = 0.f, d3 = 0.f;
    int i = r0;
    for (; i + 4 <= r1; i += 4) {
        int s0 = colidx[i], s1 = colidx[i + 1], s2 = colidx[i + 2], s3 = colidx[i + 3];
        ushort4 v0 = *(const ushort4*)&He[(size_t)s0 * 256 + c4];
        ushort4 v1 = *(const ushort4*)&He[(size_t)s1 * 256 + c4];
        ushort4 v2 = *(const ushort4*)&He[(size_t)s2 * 256 + c4];
        ushort4 v3 = *(const ushort4*)&He[(size_t)s3 * 256 + c4];
        a0 += b2f(v0.x); a1 += b2f(v0.y); a2 += b2f(v0.z); a3 += b2f(v0.w);
        b0 += b2f(v1.x); b1 += b2f(v1.y); b2 += b2f(v1.z); b3 += b2f(v1.w);
        e0 += b2f(v2.x); e1 += b2f(v2.y); e2 += b2f(v2.z); e3 += b2f(v2.w);
        d0 += b2f(v3.x); d1 += b2f(v3.y); d2 += b2f(v3.z); d3 += b2f(v3.w);
    }
    for (; i < r1; ++i) {
        int sn = colidx[i];
        ushort4 v = *(const ushort4*)&He[(size_t)sn * 256 + c4];
        a0 += b2f(v.x); a1 += b2f(v.y); a2 += b2f(v.z); a3 += b2f(v.w);
    }
    a0 += b0 + e0 + d0; a1 += b1 + e1 + d1;
    a2 += b2 + e2 + d2; a3 += b3 + e3 + d3;
    int deg = r1 - r0;
    float inv = 1.f / (float)(deg > 1 ? deg : 1);
    ushort4 self = *(const ushort4*)&He[(size_t)n * 256 + c4];
    ushort4 o;
    o.x = f2bf(b2f(self.x) + a0 * inv); o.y = f2bf(b2f(self.y) + a1 * inv);
    o.z = f2bf(b2f(self.z) + a2 * inv); o.w = f2bf(b2f(self.w) + a3 * inv);
    *(ushort4*)&X[(size_t)n * 256 + c4] = o;
}

// ------------------------------------------------ out = Ys[0] + Ys[1]
__global__ __launch_bounds__(256) void k_combine2(const float* __restrict__ Ys,
                                                  float* __restrict__ out)
{
    int i = (blockIdx.x * 256 + threadIdx.x) * 4;
    float4 a = *(const float4*)&Ys[i];
    float4 b = *(const float4*)&Ys[(size_t)NN * 256 + i];
    float4 o;
    o.x = a.x + b.x; o.y = a.y + b.y; o.z = a.z + b.z; o.w = a.w + b.w;
    *(float4*)&out[i] = o;
}

// ==========================================================================
extern "C" void kernel_launch(void* const* d_in, const int* in_sizes, int n_in,
                              void* d_out, int out_size, void* d_ws, size_t ws_size,
                              hipStream_t stream)
{
    (void)n_in; (void)out_size;
    const float* x     = (const float*)d_in[0];
    const int*   ei    = (const int*)d_in[1];
    const int*   batch = (const int*)d_in[2];
    const float* encW  = (const float*)d_in[3];
    const float* encb  = (const float*)d_in[4];
    const float* qW    = (const float*)d_in[5];
    const float* qb    = (const float*)d_in[6];
    const float* kW    = (const float*)d_in[7];
    const float* kb    = (const float*)d_in[8];
    const float* vW    = (const float*)d_in[9];
    const float* vb    = (const float*)d_in[10];
    const float* outW  = (const float*)d_in[11];
    const float* outb  = (const float*)d_in[12];
    const float* eWh   = (const float*)d_in[13];
    const float* ebh   = (const float*)d_in[14];
    const float* eWo   = (const float*)d_in[15];
    const float* ebo   = (const float*)d_in[16];
    float* out = (float*)d_out;
    if (in_sizes[0] != NN * 6 || in_sizes[1] != 2 * NE) return;

    char* wsp = (char*)d_ws;
    size_t off = 0;
    auto alloc = [&](size_t bytes) -> void* {
        void* p = wsp + off;
        off += (bytes + 511) & ~(size_t)511;
        return p;
    };
    _Float16* zh = (_Float16*)alloc((size_t)NN * ZK * 2);
    _Float16* zl = (_Float16*)alloc((size_t)NN * ZK * 2);
    unsigned short* zb = (unsigned short*)alloc((size_t)NN * 256 * 2);
    // 16MB block: q/k split-fp16; reused as Ys (2 x NN x 256 fp32) after attn
    _Float16* qh = (_Float16*)alloc((size_t)4 * NN * 256 * 2);
    _Float16* ql = qh + (size_t)NN * 256;
    _Float16* kh = ql + (size_t)NN * 256;
    _Float16* kl = kh + (size_t)NN * 256;
    float* Ys = (float*)qh;
    float* vo     = (float*)alloc((size_t)NN * 8 * 4);
    float* sparse = (float*)alloc((size_t)NN * 8 * 4);
    int*   i1buf  = (int*)alloc((size_t)NN * 4);
    unsigned short* Xball = (unsigned short*)alloc((size_t)8 * NN * 256 * 2);
    unsigned short* Heb   = (unsigned short*)alloc((size_t)8 * NN * 256 * 2);
    unsigned short* Bth   = (unsigned short*)alloc((size_t)16 * 65536 * 2);
    unsigned short* Bto   = (unsigned short*)alloc((size_t)8 * 65536 * 2);
    _Float16* Wth = (_Float16*)alloc((size_t)2 * 256 * ZK * 2);
    _Float16* Wtl = (_Float16*)alloc((size_t)2 * 256 * ZK * 2);
    float* Wvo  = (float*)alloc((size_t)ZK * 8 * 4);
    float* bvo  = (float*)alloc(8 * 4);
    float* pm   = (float*)alloc((size_t)ASPLIT * NN * 4);
    float* plb  = (float*)alloc((size_t)ASPLIT * NN * 4);
    float* pacc = (float*)alloc((size_t)ASPLIT * NN * 8 * 4);
    int* ints   = (int*)alloc((size_t)(NG + NG + NN + NN) * 4);
    int* ncnt = ints, *ecnt = ints + NG, *indeg = ecnt + NG, *cursor = indeg + NN;
    int* rowptr = (int*)alloc((size_t)(NN + 1) * 4);
    int* colidx = (int*)alloc((size_t)NE * 4);
    if (off > ws_size) return;

    hipMemsetAsync(ints, 0, (size_t)(NG + NG + NN + NN) * 4, stream);
    k_counts<<<64, 256, 0, stream>>>(ei, batch, ncnt, ecnt, indeg);
    k_prep_qkw<<<(2 * 256 * ZK) / 256, 256, 0, stream>>>(qW, kW, Wth, Wtl);
    k_prep_vo<<<(ZK * 8 + 8 + 255) / 256, 256, 0, stream>>>(vW, vb, outW, Wvo, bvo);
    k_prep_w<<<(24 * 65536) / 256, 256, 0, stream>>>(eWh, eWo, Bth, Bto);
    k_encoder<<<NN, 256, 0, stream>>>(x, encW, encb, batch, ncnt, ecnt, zh, zl, zb);
    k_scan<<<1, 256, 0, stream>>>(indeg, rowptr);
    k_fill<<<(NE + 255) / 256, 256, 0, stream>>>(ei, rowptr, cursor, colidx);

    float scale = 1.f / sqrtf(258.f);
    k_gemm_qk<<<256, 512, 0, stream>>>(zh, zl, Wth, Wtl, qb, kb,
                                       qh, ql, kh, kl, scale);
    k_vo<<<NN / 4, 256, 0, stream>>>(zh, zl, Wvo, bvo, vo);

    k_attn_mfma<<<(NN / QB) * ASPLIT, 1024, 0, stream>>>(qh, ql, kh, kl, vo, pm, plb, pacc);
    k_attn_merge<<<NN / 256, 256, 0, stream>>>(pm, plb, pacc, outb, sparse, i1buf);

    // ---- experts: 3 batched agg + 3 batched MFMA GEMMs + combine ----
    k_agg_b2b<<<NN / 4, 256, 0, stream>>>(zb, rowptr, colidx, Xball, 0);  // slot 0
    // layer 1: shared A (Xball slot 0)
    k_gemm_bf<<<1024, 512, 0, stream>>>(Xball, Bth, ebh, Heb, nullptr, nullptr, nullptr,
                                        0, (long long)2 * 65536, (long long)NN * 256,
                                        2 * 256, 0);
    // layer 2
    k_agg_b2b<<<(NN / 4) * 8, 256, 0, stream>>>(Heb, rowptr, colidx, Xball, 3);
    k_gemm_bf<<<1024, 512, 0, stream>>>(Xball, Bth + 65536, ebh + 256, Heb,
                                        nullptr, nullptr, nullptr,
                                        (long long)NN * 256, (long long)2 * 65536,
                                        (long long)NN * 256, 2 * 256, 0);
    // layer 3 -> top-2 slot buffers
    k_agg_b2b<<<(NN / 4) * 8, 256, 0, stream>>>(Heb, rowptr, colidx, Xball, 3);
    k_gemm_bf<<<1024, 512, 0, stream>>>(Xball, Bto, ebo, nullptr, Ys, sparse, i1buf,
                                        (long long)NN * 256, (long long)65536,
                                        0, 256, 1);
    k_combine2<<<(NN * 256 / 4) / 256, 256, 0, stream>>>(Ys, out);
}

// Round 13
// 976.161 us; speedup vs baseline: 1.0080x; 1.0080x over previous
//
#include <hip/hip_runtime.h>
#include <math.h>

#define NN 8192      // nodes
#define NE 131072    // edges
#define ZK 288       // padded z width (258 -> 288, multiple of 32)
#define NG 64        // graphs
#define ASPLIT 16    // attention split-K (split = bid&15)
#define QB 512       // q-rows per attention block (16 waves x 32)
#define KB 32        // keys per attention chunk

typedef __attribute__((ext_vector_type(8))) short bf16x8;
typedef __attribute__((ext_vector_type(4))) float f32x4;
typedef __attribute__((ext_vector_type(8))) _Float16 f16x8;
typedef __attribute__((ext_vector_type(4))) _Float16 f16x4;

static __device__ __forceinline__ unsigned short f2bf(float f) {
    unsigned u = __float_as_uint(f);
    unsigned r = (u + 0x7FFFu + ((u >> 16) & 1u)) >> 16;   // RNE
    return (unsigned short)r;
}
static __device__ __forceinline__ float b2f(unsigned short h) {
    return __uint_as_float(((unsigned)h) << 16);
}

// ------------------------- counts via per-block LDS histograms (G12)
__global__ __launch_bounds__(256) void k_counts(const int* __restrict__ ei,
    const int* __restrict__ batch, int* ncnt, int* ecnt, int* indeg)
{
    __shared__ int he[NG], hn[NG];
    const int t = threadIdx.x, b = blockIdx.x;
    if (t < NG) { he[t] = 0; hn[t] = 0; }
    __syncthreads();
    const int e0 = b * (NE / 64);
#pragma unroll
    for (int i = 0; i < (NE / 64) / 256; ++i) {
        int idx = e0 + i * 256 + t;
        int src = ei[idx], dst = ei[NE + idx];
        atomicAdd(&he[batch[src]], 1);
        atomicAdd(&indeg[dst], 1);
    }
    if (t < 128) atomicAdd(&hn[batch[b * 128 + t]], 1);
    __syncthreads();
    if (t < NG) {
        if (he[t]) atomicAdd(&ecnt[t], he[t]);
        if (hn[t]) atomicAdd(&ncnt[t], hn[t]);
    }
}

// -------- encoder + size feats -> zh/zl (split-fp16, ZK) and zb (bf16, 256)
__global__ __launch_bounds__(256) void k_encoder(const float* __restrict__ x,
    const float* __restrict__ encW, const float* __restrict__ encb,
    const int* __restrict__ batch, const int* __restrict__ ncnt,
    const int* __restrict__ ecnt, _Float16* __restrict__ zh,
    _Float16* __restrict__ zl, unsigned short* __restrict__ zb)
{
    int n = blockIdx.x, c = threadIdx.x;
    __shared__ float xr[8];
    if (c < 6) xr[c] = x[n * 6 + c];
    __syncthreads();
    float a = encb[c];
#pragma unroll
    for (int i = 0; i < 6; ++i) a = fmaf(xr[i], encW[i * 256 + c], a);
    float h = fmaxf(a, 0.f);
    _Float16 hi = (_Float16)h;
    zh[(size_t)n * ZK + c] = hi;
    zl[(size_t)n * ZK + c] = (_Float16)(h - (float)hi);
    zb[n * 256 + c] = f2bf(h);
    if (c == 0) {
        int g = batch[n];
        float s0 = log1pf((float)ncnt[g]);
        float s1 = log1pf((float)ecnt[g]);
        _Float16 h0 = (_Float16)s0, h1 = (_Float16)s1;
        zh[(size_t)n * ZK + 256] = h0;
        zl[(size_t)n * ZK + 256] = (_Float16)(s0 - (float)h0);
        zh[(size_t)n * ZK + 257] = h1;
        zl[(size_t)n * ZK + 257] = (_Float16)(s1 - (float)h1);
    }
    if (c >= 2 && c < 32) {                       // zero pad 258..287
        zh[(size_t)n * ZK + 256 + c] = (_Float16)0.f;
        zl[(size_t)n * ZK + 256 + c] = (_Float16)0.f;
    }
}

// ---------------------------------------------------------------- CSR build
__global__ __launch_bounds__(256) void k_scan(const int* __restrict__ indeg,
                                              int* __restrict__ rowptr)
{
    __shared__ int part[256];
    int t = threadIdx.x;
    int base = t * 32, s = 0;
    for (int i = 0; i < 32; ++i) s += indeg[base + i];
    part[t] = s;
    __syncthreads();
    if (t == 0) {
        int run = 0;
        for (int i = 0; i < 256; ++i) { int v = part[i]; part[i] = run; run += v; }
        rowptr[NN] = run;
    }
    __syncthreads();
    int run = part[t];
    for (int i = 0; i < 32; ++i) { rowptr[base + i] = run; run += indeg[base + i]; }
}

__global__ __launch_bounds__(256) void k_fill(const int* __restrict__ ei,
    const int* __restrict__ rowptr, int* __restrict__ cursor, int* __restrict__ colidx)
{
    int tid = blockIdx.x * 256 + threadIdx.x;
    if (tid >= NE) return;
    int dst = ei[NE + tid];
    int pos = atomicAdd(&cursor[dst], 1);
    colidx[rowptr[dst] + pos] = ei[tid];
}

// ---------------- Wq/Wk -> split-fp16, transposed [sel][out=256][in=288]
__global__ __launch_bounds__(256) void k_prep_qkw(const float* __restrict__ qW,
    const float* __restrict__ kW, _Float16* __restrict__ Wth,
    _Float16* __restrict__ Wtl)
{
    int idx = blockIdx.x * 256 + threadIdx.x;     // 2*256*288 = 147456
    int r = idx % ZK;
    int c = (idx / ZK) & 255;
    int sel = idx / (ZK * 256);
    const float* W = sel ? kW : qW;
    float w = (r < 258) ? W[r * 256 + c] : 0.f;
    _Float16 hi = (_Float16)w;
    Wth[idx] = hi;
    Wtl[idx] = (_Float16)(w - (float)hi);
}

// W_vo = v_W @ out_W (padded to ZK rows), bvo = v_b @ out_W
__global__ __launch_bounds__(256) void k_prep_vo(const float* __restrict__ vW,
    const float* __restrict__ vb, const float* __restrict__ outW,
    float* __restrict__ Wvo, float* __restrict__ bvo)
{
    int idx = blockIdx.x * 256 + threadIdx.x;
    if (idx < ZK * 8) {
        int r = idx >> 3, e = idx & 7;
        float s = 0.f;
        if (r < 258)
            for (int c = 0; c < 256; ++c) s = fmaf(vW[r * 256 + c], outW[c * 8 + e], s);
        Wvo[idx] = s;
    } else if (idx < ZK * 8 + 8) {
        int e = idx - ZK * 8;
        float s = 0.f;
        for (int c = 0; c < 256; ++c) s = fmaf(vb[c], outW[c * 8 + e], s);
        bvo[e] = s;
    }
}

// expert weights -> bf16, transposed to [out][in] so B-frags load contiguous
__global__ __launch_bounds__(256) void k_prep_w(const float* __restrict__ eWh,
    const float* __restrict__ eWo, unsigned short* __restrict__ Bth,
    unsigned short* __restrict__ Bto)
{
    int id = blockIdx.x * 256 + threadIdx.x;
    if (id < 16 * 65536) {
        int h = id & 255, kcol = (id >> 8) & 255, m = id >> 16;  // m = e*2+l
        Bth[id] = f2bf(eWh[((size_t)m * 256 + h) * 256 + kcol]);
    } else if (id < 24 * 65536) {
        int j = id - 16 * 65536;
        int h = j & 255, o = (j >> 8) & 255, e = j >> 16;
        Bto[j] = f2bf(eWo[((size_t)e * 256 + h) * 256 + o]);
    }
}

// -------- split-fp16 MFMA GEMM for q/k: C = (z @ W + bias) * scl -> (hi,lo)
// 128x128 tile, 512 thr (8 waves 2x4), K=288 in 9 steps of 32.
// acc = Ah*Bh + Ah*Bl + Al*Bh (fp32 MFMA accum).
// 1-D grid: sel = bid&1 (q/k), tile = bid>>1 (2 n-tiles x 64 m-tiles).
__global__ __launch_bounds__(512) void k_gemm_qk(
    const _Float16* __restrict__ zh, const _Float16* __restrict__ zl,
    const _Float16* __restrict__ Wth, const _Float16* __restrict__ Wtl,
    const float* __restrict__ qb, const float* __restrict__ kb,
    _Float16* __restrict__ qho, _Float16* __restrict__ qlo,
    _Float16* __restrict__ kho, _Float16* __restrict__ klo, float scale)
{
    const int bid = blockIdx.x;
    const int sel = bid & 1;
    const int tile = bid >> 1;
    const int n0 = (tile & 1) * 128, m0 = (tile >> 1) * 128;
    const _Float16* Bh = Wth + (size_t)sel * 256 * ZK;
    const _Float16* Bl = Wtl + (size_t)sel * 256 * ZK;
    const float* bias = sel ? kb : qb;
    _Float16* Ch = sel ? kho : qho;
    _Float16* Cl = sel ? klo : qlo;
    const float scl = sel ? 1.0f : scale;
    __shared__ _Float16 Ash[128][40], Asl[128][40];
    __shared__ _Float16 Bsh[128][40], Bsl[128][40];
    const int t = threadIdx.x;
    const int wid = t >> 6, lane = t & 63;
    const int wr = wid >> 2, wc = wid & 3;
    const int lr = lane & 15, lg = lane >> 4;
    f32x4 acc[4][2];
#pragma unroll
    for (int mf = 0; mf < 4; ++mf)
#pragma unroll
        for (int nf = 0; nf < 2; ++nf) acc[mf][nf] = (f32x4){0.f, 0.f, 0.f, 0.f};

    const int rA = t >> 2, cA = t & 3;
    for (int k0 = 0; k0 < ZK; k0 += 32) {
        *(uint4*)&Ash[rA][8 * cA] = *(const uint4*)&zh[(size_t)(m0 + rA) * ZK + k0 + 8 * cA];
        *(uint4*)&Asl[rA][8 * cA] = *(const uint4*)&zl[(size_t)(m0 + rA) * ZK + k0 + 8 * cA];
        *(uint4*)&Bsh[rA][8 * cA] = *(const uint4*)&Bh[(size_t)(n0 + rA) * ZK + k0 + 8 * cA];
        *(uint4*)&Bsl[rA][8 * cA] = *(const uint4*)&Bl[(size_t)(n0 + rA) * ZK + k0 + 8 * cA];
        __syncthreads();
        f16x8 ah[4], al[4], bh[2], bl[2];
#pragma unroll
        for (int mf = 0; mf < 4; ++mf) {
            ah[mf] = *(const f16x8*)&Ash[wr * 64 + mf * 16 + lr][8 * lg];
            al[mf] = *(const f16x8*)&Asl[wr * 64 + mf * 16 + lr][8 * lg];
        }
#pragma unroll
        for (int nf = 0; nf < 2; ++nf) {
            bh[nf] = *(const f16x8*)&Bsh[wc * 32 + nf * 16 + lr][8 * lg];
            bl[nf] = *(const f16x8*)&Bsl[wc * 32 + nf * 16 + lr][8 * lg];
        }
#pragma unroll
        for (int mf = 0; mf < 4; ++mf)
#pragma unroll
            for (int nf = 0; nf < 2; ++nf) {
                acc[mf][nf] = __builtin_amdgcn_mfma_f32_16x16x32_f16(ah[mf], bh[nf], acc[mf][nf], 0, 0, 0);
                acc[mf][nf] = __builtin_amdgcn_mfma_f32_16x16x32_f16(ah[mf], bl[nf], acc[mf][nf], 0, 0, 0);
                acc[mf][nf] = __builtin_amdgcn_mfma_f32_16x16x32_f16(al[mf], bh[nf], acc[mf][nf], 0, 0, 0);
            }
        __syncthreads();
    }
#pragma unroll
    for (int mf = 0; mf < 4; ++mf)
#pragma unroll
        for (int reg = 0; reg < 4; ++reg) {
            int m = m0 + wr * 64 + mf * 16 + lg * 4 + reg;
#pragma unroll
            for (int nf = 0; nf < 2; ++nf) {
                int c = n0 + wc * 32 + nf * 16 + lr;
                float v = (acc[mf][nf][reg] + bias[c]) * scl;
                _Float16 hi = (_Float16)v;
                Ch[(size_t)m * 256 + c] = hi;
                Cl[(size_t)m * 256 + c] = (_Float16)(v - (float)hi);
            }
        }
}

// ----------------------------------------------------- bf16 MFMA GEMM
// 128x128 tile, 512 thr (8 waves as 2x4), BK=32, 16x16x32 MFMA.
// 1-D grid: expert = bid&7 (XCD-pinned), tile = bid>>3 (2 n-tiles, 64 m-tiles)
// mode 0: relu -> bf16 Cb.  mode 1: Ys[slot] = w*(acc+bias) (top-2 slots).
__global__ __launch_bounds__(512) void k_gemm_bf(
    const unsigned short* __restrict__ A,
    const unsigned short* __restrict__ Bt,
    const float* __restrict__ bias,
    unsigned short* __restrict__ Cb,
    float* __restrict__ Ys,
    const float* __restrict__ sparse,
    const int* __restrict__ i1,
    long long aStrideZ, long long btStrideZ, long long cStrideZ, int biasStrideZ,
    int mode)
{
    const int bid = blockIdx.x;
    const int ez = bid & 7;
    const int tile = bid >> 3;
    const int n0 = (tile & 1) * 128, m0 = (tile >> 1) * 128;
    A    += (size_t)ez * aStrideZ;
    Bt   += (size_t)ez * btStrideZ;
    bias += (size_t)ez * biasStrideZ;
    if (mode == 0) Cb += (size_t)ez * cStrideZ;
    __shared__ unsigned short As[128][40];
    __shared__ unsigned short Bs[128][40];
    const int t = threadIdx.x;
    const int wid = t >> 6, lane = t & 63;
    const int wr = wid >> 2, wc = wid & 3;       // 2x4 waves: 64x32 per wave
    const int lr = lane & 15, lg = lane >> 4;
    f32x4 acc[4][2];
#pragma unroll
    for (int mf = 0; mf < 4; ++mf)
#pragma unroll
        for (int nf = 0; nf < 2; ++nf) acc[mf][nf] = (f32x4){0.f, 0.f, 0.f, 0.f};

    const int rA = t >> 2, cA = t & 3;           // 128 rows x 4 col-chunks
    for (int k0 = 0; k0 < 256; k0 += 32) {
        uint4 va = *(const uint4*)&A[(size_t)(m0 + rA) * 256 + k0 + 8 * cA];
        uint4 vB = *(const uint4*)&Bt[(size_t)(n0 + rA) * 256 + k0 + 8 * cA];
        *(uint4*)&As[rA][8 * cA] = va;
        *(uint4*)&Bs[rA][8 * cA] = vB;
        __syncthreads();
        bf16x8 a[4], b[2];
#pragma unroll
        for (int mf = 0; mf < 4; ++mf)
            a[mf] = *(const bf16x8*)&As[wr * 64 + mf * 16 + lr][8 * lg];
#pragma unroll
        for (int nf = 0; nf < 2; ++nf)
            b[nf] = *(const bf16x8*)&Bs[wc * 32 + nf * 16 + lr][8 * lg];
#pragma unroll
        for (int mf = 0; mf < 4; ++mf)
#pragma unroll
            for (int nf = 0; nf < 2; ++nf)
                acc[mf][nf] = __builtin_amdgcn_mfma_f32_16x16x32_bf16(
                    a[mf], b[nf], acc[mf][nf], 0, 0, 0);
        __syncthreads();
    }
    if (mode == 0) {
#pragma unroll
        for (int mf = 0; mf < 4; ++mf)
#pragma unroll
            for (int reg = 0; reg < 4; ++reg) {
                int m = m0 + wr * 64 + mf * 16 + lg * 4 + reg;
#pragma unroll
                for (int nf = 0; nf < 2; ++nf) {
                    int c = n0 + wc * 32 + nf * 16 + lr;
                    float v = acc[mf][nf][reg] + bias[c];
                    Cb[(size_t)m * 256 + c] = f2bf(fmaxf(v, 0.f));
                }
            }
    } else {
#pragma unroll
        for (int mf = 0; mf < 4; ++mf)
#pragma unroll
            for (int reg = 0; reg < 4; ++reg) {
                int m = m0 + wr * 64 + mf * 16 + lg * 4 + reg;
                float w = sparse[m * 8 + ez];
                if (w != 0.f) {
                    int slot = (ez == i1[m]) ? 0 : 1;
                    float* dst = Ys + (size_t)slot * NN * 256 + (size_t)m * 256;
#pragma unroll
                    for (int nf = 0; nf < 2; ++nf) {
                        int c = n0 + wc * 32 + nf * 16 + lr;
                        dst[c] = w * (acc[mf][nf][reg] + bias[c]);
                    }
                }
            }
    }
}

// ------------------------------------------------------------- vo = z @ Wvo
__global__ __launch_bounds__(256) void k_vo(const _Float16* __restrict__ zh,
    const _Float16* __restrict__ zl, const float* __restrict__ Wvo,
    const float* __restrict__ bvo, float* __restrict__ vo)
{
    int n = blockIdx.x * 4 + (threadIdx.x >> 6);
    int lane = threadIdx.x & 63;
    float p[8];
#pragma unroll
    for (int e = 0; e < 8; ++e) p[e] = 0.f;
    for (int kk = lane; kk < ZK; kk += 64) {
        float zv = (float)zh[(size_t)n * ZK + kk] + (float)zl[(size_t)n * ZK + kk];
        float4 w0 = *(const float4*)&Wvo[kk * 8];
        float4 w1 = *(const float4*)&Wvo[kk * 8 + 4];
        p[0] = fmaf(zv, w0.x, p[0]); p[1] = fmaf(zv, w0.y, p[1]);
        p[2] = fmaf(zv, w0.z, p[2]); p[3] = fmaf(zv, w0.w, p[3]);
        p[4] = fmaf(zv, w1.x, p[4]); p[5] = fmaf(zv, w1.y, p[5]);
        p[6] = fmaf(zv, w1.z, p[6]); p[7] = fmaf(zv, w1.w, p[7]);
    }
#pragma unroll
    for (int msk = 1; msk <= 32; msk <<= 1)
#pragma unroll
        for (int e = 0; e < 8; ++e) p[e] += __shfl_xor(p[e], msk);
    if (lane == 0) {
#pragma unroll
        for (int e = 0; e < 8; ++e) vo[n * 8 + e] = p[e] + bvo[e];
    }
}

// ------------------- split-fp16 MFMA flash attention, swapped operands
// 1024 threads = 16 waves = 4 waves/SIMD by construction, ONE block/CU.
// launch_bounds(1024, 1): 16 waves / 4 SIMD = 4 waves/EU -> VGPR budget
// 512/4 = 128, exactly the Q-fragment footprint, no spill.
// (R12 bug: (1024,2) demanded 8 waves/SIMD -> 64-VGPR cap -> 2.8GB spill.)
// K staged via global_load_lds width=16; LDS linear, swizzle on the global
// source (rule #21).
__global__ __launch_bounds__(1024, 1) void k_attn_mfma(
    const _Float16* __restrict__ qh_, const _Float16* __restrict__ ql_,
    const _Float16* __restrict__ kh, const _Float16* __restrict__ kl,
    const float* __restrict__ vo, float* __restrict__ pm,
    float* __restrict__ pl, float* __restrict__ pacc)
{
    __shared__ uint4 lds[2][KB * 64];   // per key: 512B hi | 512B lo (16B units)
    const int bid = blockIdx.x;
    const int split = bid & 15;
    const int rowblk = bid >> 4;
    const int n0 = rowblk * QB;
    const int t = threadIdx.x, w = t >> 6, lane = t & 63;
    const int g = lane >> 4, c = lane & 15;

    // Q B-fragments (col=lane&15=row, k=8*g + st*32), persistent in registers
    f16x8 bqh[2][8], bql[2][8];
#pragma unroll
    for (int rs = 0; rs < 2; ++rs) {
        const int row = n0 + w * 32 + rs * 16 + c;
#pragma unroll
        for (int st = 0; st < 8; ++st) {
            bqh[rs][st] = *(const f16x8*)&qh_[(size_t)row * 256 + st * 32 + g * 8];
            bql[rs][st] = *(const f16x8*)&ql_[(size_t)row * 256 + st * 32 + g * 8];
        }
    }
    float m_[2] = {-INFINITY, -INFINITY};
    float l_[2] = {0.f, 0.f};
    float pv[2][8];
#pragma unroll
    for (int rs = 0; rs < 2; ++rs)
#pragma unroll
        for (int e = 0; e < 8; ++e) pv[rs][e] = 0.f;

    const int kbase0 = split * (NN / ASPLIT);
    // Direct global->LDS staging. Linear LDS unit u = i*1024 + t holds the
    // swizzled source chunk: key=u>>6, half=(u>>5)&1, c16=(u&31)^(key&7).
    auto STAGE = [&](int buf, int kb) {
#pragma unroll
        for (int i = 0; i < 2; ++i) {
            int u = i * 1024 + t;
            int key = u >> 6;
            int half = (u >> 5) & 1;
            int c16 = (u & 31) ^ (key & 7);      // pre-swizzled source
            const _Float16* src = half ? kl : kh;
            const _Float16* gp = src + (size_t)(kb + key) * 256 + c16 * 8;
            uint4* lp = &lds[buf][i * 1024 + (t & ~63)];  // wave-uniform base
            __builtin_amdgcn_global_load_lds(
                (const __attribute__((address_space(1))) void*)gp,
                (__attribute__((address_space(3))) void*)lp, 16, 0, 0);
        }
    };
    STAGE(0, kbase0);
    __syncthreads();
    int cur = 0;
    const int NCH = (NN / ASPLIT) / KB;   // 16 chunks
    for (int ch = 0; ch < NCH; ++ch) {
        const int kbase = kbase0 + ch * KB;
        if (ch + 1 < NCH) STAGE(cur ^ 1, kbase + KB);   // async; rides vmcnt
#pragma unroll
        for (int kt = 0; kt < 2; ++kt) {
            const char* kbp = (const char*)lds[cur] + (kt * 16 + c) * 1024;
            const int swz = ((kt * 16 + c) & 7) << 4;
            f32x4 acc0 = (f32x4){0.f, 0.f, 0.f, 0.f};
            f32x4 acc1 = (f32x4){0.f, 0.f, 0.f, 0.f};
            __builtin_amdgcn_s_setprio(1);
#pragma unroll
            for (int st = 0; st < 8; ++st) {
                const int off = (st * 64 + g * 16) ^ swz;
                f16x8 kah = *(const f16x8*)(kbp + off);
                f16x8 kal = *(const f16x8*)(kbp + 512 + off);
                acc0 = __builtin_amdgcn_mfma_f32_16x16x32_f16(kah, bqh[0][st], acc0, 0, 0, 0);
                acc0 = __builtin_amdgcn_mfma_f32_16x16x32_f16(kal, bqh[0][st], acc0, 0, 0, 0);
                acc0 = __builtin_amdgcn_mfma_f32_16x16x32_f16(kah, bql[0][st], acc0, 0, 0, 0);
                acc1 = __builtin_amdgcn_mfma_f32_16x16x32_f16(kah, bqh[1][st], acc1, 0, 0, 0);
                acc1 = __builtin_amdgcn_mfma_f32_16x16x32_f16(kal, bqh[1][st], acc1, 0, 0, 0);
                acc1 = __builtin_amdgcn_mfma_f32_16x16x32_f16(kah, bql[1][st], acc1, 0, 0, 0);
            }
            __builtin_amdgcn_s_setprio(0);
            const int kb2 = kbase + kt * 16 + 4 * g;
            float4 w0[4], w1[4];
#pragma unroll
            for (int r = 0; r < 4; ++r) {
                w0[r] = *(const float4*)&vo[(kb2 + r) * 8];
                w1[r] = *(const float4*)&vo[(kb2 + r) * 8 + 4];
            }
#pragma unroll
            for (int rs = 0; rs < 2; ++rs) {
                f32x4 s = rs ? acc1 : acc0;
                float cm = fmaxf(fmaxf(s[0], s[1]), fmaxf(s[2], s[3]));
                float mn = fmaxf(m_[rs], cm);
                float rsc = __expf(m_[rs] - mn);
                float p0 = __expf(s[0] - mn);
                float p1 = __expf(s[1] - mn);
                float p2 = __expf(s[2] - mn);
                float p3 = __expf(s[3] - mn);
                l_[rs] = l_[rs] * rsc + (p0 + p1 + p2 + p3);
                m_[rs] = mn;
                pv[rs][0] = pv[rs][0]*rsc + p0*w0[0].x + p1*w0[1].x + p2*w0[2].x + p3*w0[3].x;
                pv[rs][1] = pv[rs][1]*rsc + p0*w0[0].y + p1*w0[1].y + p2*w0[2].y + p3*w0[3].y;
                pv[rs][2] = pv[rs][2]*rsc + p0*w0[0].z + p1*w0[1].z + p2*w0[2].z + p3*w0[3].z;
                pv[rs][3] = pv[rs][3]*rsc + p0*w0[0].w + p1*w0[1].w + p2*w0[2].w + p3*w0[3].w;
                pv[rs][4] = pv[rs][4]*rsc + p0*w1[0].x + p1*w1[1].x + p2*w1[2].x + p3*w1[3].x;
                pv[rs][5] = pv[rs][5]*rsc + p0*w1[0].y + p1*w1[1].y + p2*w1[2].y + p3*w1[3].y;
                pv[rs][6] = pv[rs][6]*rsc + p0*w1[0].z + p1*w1[1].z + p2*w1[2].z + p3*w1[3].z;
                pv[rs][7] = pv[rs][7]*rsc + p0*w1[0].w + p1*w1[1].w + p2*w1[2].w + p3*w1[3].w;
            }
        }
        __syncthreads();
        cur ^= 1;
    }
    // --- merge across the 4 lanes (g=0..3) sharing each q-row ---
#pragma unroll
    for (int msk = 16; msk <= 32; msk <<= 1) {
#pragma unroll
        for (int rs = 0; rs < 2; ++rs) {
            float mo = __shfl_xor(m_[rs], msk);
            float lo = __shfl_xor(l_[rs], msk);
            float mn = fmaxf(m_[rs], mo);
            float a = __expf(m_[rs] - mn), b = __expf(mo - mn);
            l_[rs] = l_[rs] * a + lo * b;
#pragma unroll
            for (int e = 0; e < 8; ++e) {
                float po = __shfl_xor(pv[rs][e], msk);
                pv[rs][e] = pv[rs][e] * a + po * b;
            }
            m_[rs] = mn;
        }
    }
    if (g == 0) {
#pragma unroll
        for (int rs = 0; rs < 2; ++rs) {
            int n = n0 + w * 32 + rs * 16 + c;
            pm[split * NN + n] = m_[rs];
            pl[split * NN + n] = l_[rs];
#pragma unroll
            for (int e = 0; e < 8; ++e)
                pacc[(size_t)split * NN * 8 + n * 8 + e] = pv[rs][e];
        }
    }
}

// ----------------------------------- merge split-K partials -> top2 weights
__global__ __launch_bounds__(256) void k_attn_merge(
    const float* __restrict__ pm, const float* __restrict__ pl,
    const float* __restrict__ pacc, const float* __restrict__ outb,
    float* __restrict__ sparse, int* __restrict__ i1o)
{
    int n = blockIdx.x * 256 + threadIdx.x;
    float mn = -INFINITY;
#pragma unroll
    for (int s = 0; s < ASPLIT; ++s) mn = fmaxf(mn, pm[s * NN + n]);
    float l = 0.f;
    float lg[8];
#pragma unroll
    for (int e = 0; e < 8; ++e) lg[e] = 0.f;
#pragma unroll
    for (int s = 0; s < ASPLIT; ++s) {
        float r = __expf(pm[s * NN + n] - mn);
        l += pl[s * NN + n] * r;
#pragma unroll
        for (int e = 0; e < 8; ++e)
            lg[e] += pacc[(size_t)s * NN * 8 + n * 8 + e] * r;
    }
    float inv = 1.f / l;
#pragma unroll
    for (int e = 0; e < 8; ++e) lg[e] = lg[e] * inv + outb[e];
    int i1 = 0; float v1 = lg[0];
#pragma unroll
    for (int e = 1; e < 8; ++e) if (lg[e] > v1) { v1 = lg[e]; i1 = e; }
    int i2 = -1; float v2 = -INFINITY;
#pragma unroll
    for (int e = 0; e < 8; ++e) if (e != i1 && lg[e] > v2) { v2 = lg[e]; i2 = e; }
    float e2 = __expf(v2 - v1);
    float w1 = 1.f / (1.f + e2);
    float w2 = e2 / (1.f + e2);
#pragma unroll
    for (int e = 0; e < 8; ++e)
        sparse[n * 8 + e] = (e == i1) ? w1 : ((e == i2) ? w2 : 0.f);
    i1o[n] = i1;
}

// ------------------- bf16 gather-mean: X = bf16(src + neigh_mean(src))
// 1-D grid: expert = bid & ((1<<eshift)-1) (XCD-pinned), node-blk = bid>>eshift
// 4-way unrolled gather: 4 row-loads in flight, 4 independent accumulators.
__global__ __launch_bounds__(256) void k_agg_b2b(
    const unsigned short* __restrict__ HeAll, const int* __restrict__ rowptr,
    const int* __restrict__ colidx, unsigned short* __restrict__ XAll,
    int eshift)
{
    const int bid = blockIdx.x;
    const int e = bid & ((1 << eshift) - 1);
    const int nb = bid >> eshift;
    const unsigned short* He = HeAll + (size_t)e * NN * 256;
    unsigned short* X = XAll + (size_t)e * NN * 256;
    int n = nb * 4 + (threadIdx.x >> 6);
    int c4 = (threadIdx.x & 63) * 4;
    int r0 = rowptr[n], r1 = rowptr[n + 1];
    float a0 = 0.f, a1 = 0.f, a2 = 0.f, a3 = 0.f;
    float b0 = 0.f, b1 = 0.f, b2 = 0.f, b3 = 0.f;
    float e0 = 0.f, e1 = 0.f, e2 = 0.f, e3 = 0.f;
    float d0 = 0.f, d1 = 0.f, d2 = 0.f, d3 = 0.f;
    int i = r0;
    for (; i + 4 <= r1; i += 4) {
        int s0 = colidx[i], s1 = colidx[i + 1], s2 = colidx[i + 2], s3 = colidx[i + 3];
        ushort4 v0 = *(const ushort4*)&He[(size_t)s0 * 256 + c4];
        ushort4 v1 = *(const ushort4*)&He[(size_t)s1 * 256 + c4];
        ushort4 v2 = *(const ushort4*)&He[(size_t)s2 * 256 + c4];
        ushort4 v3 = *(const ushort4*)&He[(size_t)s3 * 256 + c4];
        a0 += b2f(v0.x); a1 += b2f(v0.y); a2 += b2f(v0.z); a3 += b2f(v0.w);
        b0 += b2f(v1.x); b1 += b2f(v1.y); b2 += b2f(v1.z); b3 += b2f(v1.w);
        e0 += b2f(v2.x); e1 += b2f(v2.y); e2 += b2f(v2.z); e3 += b2f(v2.w);
        d0 += b2f(v3.x); d1 += b2f(v3.y); d2 += b2f(v3.z); d3 += b2f(v3.w);
    }
    for (; i < r1; ++i) {
        int sn = colidx[i];
        ushort4 v = *(const ushort4*)&He[(size_t)sn * 256 + c4];
        a0 += b2f(v.x); a1 += b2f(v.y); a2 += b2f(v.z); a3 += b2f(v.w);
    }
    a0 += b0 + e0 + d0; a1 += b1 + e1 + d1;
    a2 += b2 + e2 + d2; a3 += b3 + e3 + d3;
    int deg = r1 - r0;
    float inv = 1.f / (float)(deg > 1 ? deg : 1);
    ushort4 self = *(const ushort4*)&He[(size_t)n * 256 + c4];
    ushort4 o;
    o.x = f2bf(b2f(self.x) + a0 * inv); o.y = f2bf(b2f(self.y) + a1 * inv);
    o.z = f2bf(b2f(self.z) + a2 * inv); o.w = f2bf(b2f(self.w) + a3 * inv);
    *(ushort4*)&X[(size_t)n * 256 + c4] = o;
}

// ------------------------------------------------ out = Ys[0] + Ys[1]
__global__ __launch_bounds__(256) void k_combine2(const float* __restrict__ Ys,
                                                  float* __restrict__ out)
{
    int i = (blockIdx.x * 256 + threadIdx.x) * 4;
    float4 a = *(const float4*)&Ys[i];
    float4 b = *(const float4*)&Ys[(size_t)NN * 256 + i];
    float4 o;
    o.x = a.x + b.x; o.y = a.y + b.y; o.z = a.z + b.z; o.w = a.w + b.w;
    *(float4*)&out[i] = o;
}

// ==========================================================================
extern "C" void kernel_launch(void* const* d_in, const int* in_sizes, int n_in,
                              void* d_out, int out_size, void* d_ws, size_t ws_size,
                              hipStream_t stream)
{
    (void)n_in; (void)out_size;
    const float* x     = (const float*)d_in[0];
    const int*   ei    = (const int*)d_in[1];
    const int*   batch = (const int*)d_in[2];
    const float* encW  = (const float*)d_in[3];
    const float* encb  = (const float*)d_in[4];
    const float* qW    = (const float*)d_in[5];
    const float* qb    = (const float*)d_in[6];
    const float* kW    = (const float*)d_in[7];
    const float* kb    = (const float*)d_in[8];
    const float* vW    = (const float*)d_in[9];
    const float* vb    = (const float*)d_in[10];
    const float* outW  = (const float*)d_in[11];
    const float* outb  = (const float*)d_in[12];
    const float* eWh   = (const float*)d_in[13];
    const float* ebh   = (const float*)d_in[14];
    const float* eWo   = (const float*)d_in[15];
    const float* ebo   = (const float*)d_in[16];
    float* out = (float*)d_out;
    if (in_sizes[0] != NN * 6 || in_sizes[1] != 2 * NE) return;

    char* wsp = (char*)d_ws;
    size_t off = 0;
    auto alloc = [&](size_t bytes) -> void* {
        void* p = wsp + off;
        off += (bytes + 511) & ~(size_t)511;
        return p;
    };
    _Float16* zh = (_Float16*)alloc((size_t)NN * ZK * 2);
    _Float16* zl = (_Float16*)alloc((size_t)NN * ZK * 2);
    unsigned short* zb = (unsigned short*)alloc((size_t)NN * 256 * 2);
    // 16MB block: q/k split-fp16; reused as Ys (2 x NN x 256 fp32) after attn
    _Float16* qh = (_Float16*)alloc((size_t)4 * NN * 256 * 2);
    _Float16* ql = qh + (size_t)NN * 256;
    _Float16* kh = ql + (size_t)NN * 256;
    _Float16* kl = kh + (size_t)NN * 256;
    float* Ys = (float*)qh;
    float* vo     = (float*)alloc((size_t)NN * 8 * 4);
    float* sparse = (float*)alloc((size_t)NN * 8 * 4);
    int*   i1buf  = (int*)alloc((size_t)NN * 4);
    unsigned short* Xball = (unsigned short*)alloc((size_t)8 * NN * 256 * 2);
    unsigned short* Heb   = (unsigned short*)alloc((size_t)8 * NN * 256 * 2);
    unsigned short* Bth   = (unsigned short*)alloc((size_t)16 * 65536 * 2);
    unsigned short* Bto   = (unsigned short*)alloc((size_t)8 * 65536 * 2);
    _Float16* Wth = (_Float16*)alloc((size_t)2 * 256 * ZK * 2);
    _Float16* Wtl = (_Float16*)alloc((size_t)2 * 256 * ZK * 2);
    float* Wvo  = (float*)alloc((size_t)ZK * 8 * 4);
    float* bvo  = (float*)alloc(8 * 4);
    float* pm   = (float*)alloc((size_t)ASPLIT * NN * 4);
    float* plb  = (float*)alloc((size_t)ASPLIT * NN * 4);
    float* pacc = (float*)alloc((size_t)ASPLIT * NN * 8 * 4);
    int* ints   = (int*)alloc((size_t)(NG + NG + NN + NN) * 4);
    int* ncnt = ints, *ecnt = ints + NG, *indeg = ecnt + NG, *cursor = indeg + NN;
    int* rowptr = (int*)alloc((size_t)(NN + 1) * 4);
    int* colidx = (int*)alloc((size_t)NE * 4);
    if (off > ws_size) return;

    hipMemsetAsync(ints, 0, (size_t)(NG + NG + NN + NN) * 4, stream);
    k_counts<<<64, 256, 0, stream>>>(ei, batch, ncnt, ecnt, indeg);
    k_prep_qkw<<<(2 * 256 * ZK) / 256, 256, 0, stream>>>(qW, kW, Wth, Wtl);
    k_prep_vo<<<(ZK * 8 + 8 + 255) / 256, 256, 0, stream>>>(vW, vb, outW, Wvo, bvo);
    k_prep_w<<<(24 * 65536) / 256, 256, 0, stream>>>(eWh, eWo, Bth, Bto);
    k_encoder<<<NN, 256, 0, stream>>>(x, encW, encb, batch, ncnt, ecnt, zh, zl, zb);
    k_scan<<<1, 256, 0, stream>>>(indeg, rowptr);
    k_fill<<<(NE + 255) / 256, 256, 0, stream>>>(ei, rowptr, cursor, colidx);

    float scale = 1.f / sqrtf(258.f);
    k_gemm_qk<<<256, 512, 0, stream>>>(zh, zl, Wth, Wtl, qb, kb,
                                       qh, ql, kh, kl, scale);
    k_vo<<<NN / 4, 256, 0, stream>>>(zh, zl, Wvo, bvo, vo);

    k_attn_mfma<<<(NN / QB) * ASPLIT, 1024, 0, stream>>>(qh, ql, kh, kl, vo, pm, plb, pacc);
    k_attn_merge<<<NN / 256, 256, 0, stream>>>(pm, plb, pacc, outb, sparse, i1buf);

    // ---- experts: 3 batched agg + 3 batched MFMA GEMMs + combine ----
    k_agg_b2b<<<NN / 4, 256, 0, stream>>>(zb, rowptr, colidx, Xball, 0);  // slot 0
    // layer 1: shared A (Xball slot 0)
    k_gemm_bf<<<1024, 512, 0, stream>>>(Xball, Bth, ebh, Heb, nullptr, nullptr, nullptr,
                                        0, (long long)2 * 65536, (long long)NN * 256,
                                        2 * 256, 0);
    // layer 2
    k_agg_b2b<<<(NN / 4) * 8, 256, 0, stream>>>(Heb, rowptr, colidx, Xball, 3);
    k_gemm_bf<<<1024, 512, 0, stream>>>(Xball, Bth + 65536, ebh + 256, Heb,
                                        nullptr, nullptr, nullptr,
                                        (long long)NN * 256, (long long)2 * 65536,
                                        (long long)NN * 256, 2 * 256, 0);
    // layer 3 -> top-2 slot buffers
    k_agg_b2b<<<(NN / 4) * 8, 256, 0, stream>>>(Heb, rowptr, colidx, Xball, 3);
    k_gemm_bf<<<1024, 512, 0, stream>>>(Xball, Bto, ebo, nullptr, Ys, sparse, i1buf,
                                        (long long)NN * 256, (long long)65536,
                                        0, 256, 1);
    k_combine2<<<(NN * 256 / 4) / 256, 256, 0, stream>>>(Ys, out);
}

// Round 14
// 393.246 us; speedup vs baseline: 2.5021x; 2.4823x over previous
//
#include <hip/hip_runtime.h>
#include <math.h>

#define NN 8192      // nodes
#define NE 131072    // edges
#define ZK 288       // padded z width (258 -> 288, multiple of 32)
#define NG 64        // graphs
#define ASPLIT 16    // attention split-K (split = bid&15)
#define QB 256       // q-rows per attention block (8 waves x 32)
#define KB 16        // keys per attention chunk (32KB LDS: test 2-block/CU)

typedef __attribute__((ext_vector_type(8))) short bf16x8;
typedef __attribute__((ext_vector_type(4))) float f32x4;
typedef __attribute__((ext_vector_type(8))) _Float16 f16x8;
typedef __attribute__((ext_vector_type(4))) _Float16 f16x4;

static __device__ __forceinline__ unsigned short f2bf(float f) {
    unsigned u = __float_as_uint(f);
    unsigned r = (u + 0x7FFFu + ((u >> 16) & 1u)) >> 16;   // RNE
    return (unsigned short)r;
}
static __device__ __forceinline__ float b2f(unsigned short h) {
    return __uint_as_float(((unsigned)h) << 16);
}

// ------------------------- counts via per-block LDS histograms (G12)
__global__ __launch_bounds__(256) void k_counts(const int* __restrict__ ei,
    const int* __restrict__ batch, int* ncnt, int* ecnt, int* indeg)
{
    __shared__ int he[NG], hn[NG];
    const int t = threadIdx.x, b = blockIdx.x;
    if (t < NG) { he[t] = 0; hn[t] = 0; }
    __syncthreads();
    const int e0 = b * (NE / 64);
#pragma unroll
    for (int i = 0; i < (NE / 64) / 256; ++i) {
        int idx = e0 + i * 256 + t;
        int src = ei[idx], dst = ei[NE + idx];
        atomicAdd(&he[batch[src]], 1);
        atomicAdd(&indeg[dst], 1);
    }
    if (t < 128) atomicAdd(&hn[batch[b * 128 + t]], 1);
    __syncthreads();
    if (t < NG) {
        if (he[t]) atomicAdd(&ecnt[t], he[t]);
        if (hn[t]) atomicAdd(&ncnt[t], hn[t]);
    }
}

// -------- encoder + size feats -> zh/zl (split-fp16, ZK) and zb (bf16, 256)
__global__ __launch_bounds__(256) void k_encoder(const float* __restrict__ x,
    const float* __restrict__ encW, const float* __restrict__ encb,
    const int* __restrict__ batch, const int* __restrict__ ncnt,
    const int* __restrict__ ecnt, _Float16* __restrict__ zh,
    _Float16* __restrict__ zl, unsigned short* __restrict__ zb)
{
    int n = blockIdx.x, c = threadIdx.x;
    __shared__ float xr[8];
    if (c < 6) xr[c] = x[n * 6 + c];
    __syncthreads();
    float a = encb[c];
#pragma unroll
    for (int i = 0; i < 6; ++i) a = fmaf(xr[i], encW[i * 256 + c], a);
    float h = fmaxf(a, 0.f);
    _Float16 hi = (_Float16)h;
    zh[(size_t)n * ZK + c] = hi;
    zl[(size_t)n * ZK + c] = (_Float16)(h - (float)hi);
    zb[n * 256 + c] = f2bf(h);
    if (c == 0) {
        int g = batch[n];
        float s0 = log1pf((float)ncnt[g]);
        float s1 = log1pf((float)ecnt[g]);
        _Float16 h0 = (_Float16)s0, h1 = (_Float16)s1;
        zh[(size_t)n * ZK + 256] = h0;
        zl[(size_t)n * ZK + 256] = (_Float16)(s0 - (float)h0);
        zh[(size_t)n * ZK + 257] = h1;
        zl[(size_t)n * ZK + 257] = (_Float16)(s1 - (float)h1);
    }
    if (c >= 2 && c < 32) {                       // zero pad 258..287
        zh[(size_t)n * ZK + 256 + c] = (_Float16)0.f;
        zl[(size_t)n * ZK + 256 + c] = (_Float16)0.f;
    }
}

// ---------------------------------------------------------------- CSR build
__global__ __launch_bounds__(256) void k_scan(const int* __restrict__ indeg,
                                              int* __restrict__ rowptr)
{
    __shared__ int part[256];
    int t = threadIdx.x;
    int base = t * 32, s = 0;
    for (int i = 0; i < 32; ++i) s += indeg[base + i];
    part[t] = s;
    __syncthreads();
    if (t == 0) {
        int run = 0;
        for (int i = 0; i < 256; ++i) { int v = part[i]; part[i] = run; run += v; }
        rowptr[NN] = run;
    }
    __syncthreads();
    int run = part[t];
    for (int i = 0; i < 32; ++i) { rowptr[base + i] = run; run += indeg[base + i]; }
}

__global__ __launch_bounds__(256) void k_fill(const int* __restrict__ ei,
    const int* __restrict__ rowptr, int* __restrict__ cursor, int* __restrict__ colidx)
{
    int tid = blockIdx.x * 256 + threadIdx.x;
    if (tid >= NE) return;
    int dst = ei[NE + tid];
    int pos = atomicAdd(&cursor[dst], 1);
    colidx[rowptr[dst] + pos] = ei[tid];
}

// ---------------- Wq/Wk -> split-fp16, transposed [sel][out=256][in=288]
__global__ __launch_bounds__(256) void k_prep_qkw(const float* __restrict__ qW,
    const float* __restrict__ kW, _Float16* __restrict__ Wth,
    _Float16* __restrict__ Wtl)
{
    int idx = blockIdx.x * 256 + threadIdx.x;     // 2*256*288 = 147456
    int r = idx % ZK;
    int c = (idx / ZK) & 255;
    int sel = idx / (ZK * 256);
    const float* W = sel ? kW : qW;
    float w = (r < 258) ? W[r * 256 + c] : 0.f;
    _Float16 hi = (_Float16)w;
    Wth[idx] = hi;
    Wtl[idx] = (_Float16)(w - (float)hi);
}

// W_vo = v_W @ out_W (padded to ZK rows), bvo = v_b @ out_W
__global__ __launch_bounds__(256) void k_prep_vo(const float* __restrict__ vW,
    const float* __restrict__ vb, const float* __restrict__ outW,
    float* __restrict__ Wvo, float* __restrict__ bvo)
{
    int idx = blockIdx.x * 256 + threadIdx.x;
    if (idx < ZK * 8) {
        int r = idx >> 3, e = idx & 7;
        float s = 0.f;
        if (r < 258)
            for (int c = 0; c < 256; ++c) s = fmaf(vW[r * 256 + c], outW[c * 8 + e], s);
        Wvo[idx] = s;
    } else if (idx < ZK * 8 + 8) {
        int e = idx - ZK * 8;
        float s = 0.f;
        for (int c = 0; c < 256; ++c) s = fmaf(vb[c], outW[c * 8 + e], s);
        bvo[e] = s;
    }
}

// expert weights -> bf16, transposed to [out][in] so B-frags load contiguous
__global__ __launch_bounds__(256) void k_prep_w(const float* __restrict__ eWh,
    const float* __restrict__ eWo, unsigned short* __restrict__ Bth,
    unsigned short* __restrict__ Bto)
{
    int id = blockIdx.x * 256 + threadIdx.x;
    if (id < 16 * 65536) {
        int h = id & 255, kcol = (id >> 8) & 255, m = id >> 16;  // m = e*2+l
        Bth[id] = f2bf(eWh[((size_t)m * 256 + h) * 256 + kcol]);
    } else if (id < 24 * 65536) {
        int j = id - 16 * 65536;
        int h = j & 255, o = (j >> 8) & 255, e = j >> 16;
        Bto[j] = f2bf(eWo[((size_t)e * 256 + h) * 256 + o]);
    }
}

// -------- split-fp16 MFMA GEMM for q/k: C = (z @ W + bias) * scl -> (hi,lo)
// 128x128 tile, 512 thr (8 waves 2x4), K=288 in 9 steps of 32.
// acc = Ah*Bh + Ah*Bl + Al*Bh (fp32 MFMA accum).
// 1-D grid: sel = bid&1 (q/k), tile = bid>>1 (2 n-tiles x 64 m-tiles).
__global__ __launch_bounds__(512) void k_gemm_qk(
    const _Float16* __restrict__ zh, const _Float16* __restrict__ zl,
    const _Float16* __restrict__ Wth, const _Float16* __restrict__ Wtl,
    const float* __restrict__ qb, const float* __restrict__ kb,
    _Float16* __restrict__ qho, _Float16* __restrict__ qlo,
    _Float16* __restrict__ kho, _Float16* __restrict__ klo, float scale)
{
    const int bid = blockIdx.x;
    const int sel = bid & 1;
    const int tile = bid >> 1;
    const int n0 = (tile & 1) * 128, m0 = (tile >> 1) * 128;
    const _Float16* Bh = Wth + (size_t)sel * 256 * ZK;
    const _Float16* Bl = Wtl + (size_t)sel * 256 * ZK;
    const float* bias = sel ? kb : qb;
    _Float16* Ch = sel ? kho : qho;
    _Float16* Cl = sel ? klo : qlo;
    const float scl = sel ? 1.0f : scale;
    __shared__ _Float16 Ash[128][40], Asl[128][40];
    __shared__ _Float16 Bsh[128][40], Bsl[128][40];
    const int t = threadIdx.x;
    const int wid = t >> 6, lane = t & 63;
    const int wr = wid >> 2, wc = wid & 3;
    const int lr = lane & 15, lg = lane >> 4;
    f32x4 acc[4][2];
#pragma unroll
    for (int mf = 0; mf < 4; ++mf)
#pragma unroll
        for (int nf = 0; nf < 2; ++nf) acc[mf][nf] = (f32x4){0.f, 0.f, 0.f, 0.f};

    const int rA = t >> 2, cA = t & 3;
    for (int k0 = 0; k0 < ZK; k0 += 32) {
        *(uint4*)&Ash[rA][8 * cA] = *(const uint4*)&zh[(size_t)(m0 + rA) * ZK + k0 + 8 * cA];
        *(uint4*)&Asl[rA][8 * cA] = *(const uint4*)&zl[(size_t)(m0 + rA) * ZK + k0 + 8 * cA];
        *(uint4*)&Bsh[rA][8 * cA] = *(const uint4*)&Bh[(size_t)(n0 + rA) * ZK + k0 + 8 * cA];
        *(uint4*)&Bsl[rA][8 * cA] = *(const uint4*)&Bl[(size_t)(n0 + rA) * ZK + k0 + 8 * cA];
        __syncthreads();
        f16x8 ah[4], al[4], bh[2], bl[2];
#pragma unroll
        for (int mf = 0; mf < 4; ++mf) {
            ah[mf] = *(const f16x8*)&Ash[wr * 64 + mf * 16 + lr][8 * lg];
            al[mf] = *(const f16x8*)&Asl[wr * 64 + mf * 16 + lr][8 * lg];
        }
#pragma unroll
        for (int nf = 0; nf < 2; ++nf) {
            bh[nf] = *(const f16x8*)&Bsh[wc * 32 + nf * 16 + lr][8 * lg];
            bl[nf] = *(const f16x8*)&Bsl[wc * 32 + nf * 16 + lr][8 * lg];
        }
#pragma unroll
        for (int mf = 0; mf < 4; ++mf)
#pragma unroll
            for (int nf = 0; nf < 2; ++nf) {
                acc[mf][nf] = __builtin_amdgcn_mfma_f32_16x16x32_f16(ah[mf], bh[nf], acc[mf][nf], 0, 0, 0);
                acc[mf][nf] = __builtin_amdgcn_mfma_f32_16x16x32_f16(ah[mf], bl[nf], acc[mf][nf], 0, 0, 0);
                acc[mf][nf] = __builtin_amdgcn_mfma_f32_16x16x32_f16(al[mf], bh[nf], acc[mf][nf], 0, 0, 0);
            }
        __syncthreads();
    }
#pragma unroll
    for (int mf = 0; mf < 4; ++mf)
#pragma unroll
        for (int reg = 0; reg < 4; ++reg) {
            int m = m0 + wr * 64 + mf * 16 + lg * 4 + reg;
#pragma unroll
            for (int nf = 0; nf < 2; ++nf) {
                int c = n0 + wc * 32 + nf * 16 + lr;
                float v = (acc[mf][nf][reg] + bias[c]) * scl;
                _Float16 hi = (_Float16)v;
                Ch[(size_t)m * 256 + c] = hi;
                Cl[(size_t)m * 256 + c] = (_Float16)(v - (float)hi);
            }
        }
}

// ----------------------------------------------------- bf16 MFMA GEMM
// 128x128 tile, 512 thr (8 waves as 2x4), BK=32, 16x16x32 MFMA.
// 1-D grid: expert = bid&7 (XCD-pinned), tile = bid>>3 (2 n-tiles, 64 m-tiles)
// mode 0: relu -> bf16 Cb.  mode 1: Ys[slot] = w*(acc+bias) (top-2 slots).
__global__ __launch_bounds__(512) void k_gemm_bf(
    const unsigned short* __restrict__ A,
    const unsigned short* __restrict__ Bt,
    const float* __restrict__ bias,
    unsigned short* __restrict__ Cb,
    float* __restrict__ Ys,
    const float* __restrict__ sparse,
    const int* __restrict__ i1,
    long long aStrideZ, long long btStrideZ, long long cStrideZ, int biasStrideZ,
    int mode)
{
    const int bid = blockIdx.x;
    const int ez = bid & 7;
    const int tile = bid >> 3;
    const int n0 = (tile & 1) * 128, m0 = (tile >> 1) * 128;
    A    += (size_t)ez * aStrideZ;
    Bt   += (size_t)ez * btStrideZ;
    bias += (size_t)ez * biasStrideZ;
    if (mode == 0) Cb += (size_t)ez * cStrideZ;
    __shared__ unsigned short As[128][40];
    __shared__ unsigned short Bs[128][40];
    const int t = threadIdx.x;
    const int wid = t >> 6, lane = t & 63;
    const int wr = wid >> 2, wc = wid & 3;       // 2x4 waves: 64x32 per wave
    const int lr = lane & 15, lg = lane >> 4;
    f32x4 acc[4][2];
#pragma unroll
    for (int mf = 0; mf < 4; ++mf)
#pragma unroll
        for (int nf = 0; nf < 2; ++nf) acc[mf][nf] = (f32x4){0.f, 0.f, 0.f, 0.f};

    const int rA = t >> 2, cA = t & 3;           // 128 rows x 4 col-chunks
    for (int k0 = 0; k0 < 256; k0 += 32) {
        uint4 va = *(const uint4*)&A[(size_t)(m0 + rA) * 256 + k0 + 8 * cA];
        uint4 vB = *(const uint4*)&Bt[(size_t)(n0 + rA) * 256 + k0 + 8 * cA];
        *(uint4*)&As[rA][8 * cA] = va;
        *(uint4*)&Bs[rA][8 * cA] = vB;
        __syncthreads();
        bf16x8 a[4], b[2];
#pragma unroll
        for (int mf = 0; mf < 4; ++mf)
            a[mf] = *(const bf16x8*)&As[wr * 64 + mf * 16 + lr][8 * lg];
#pragma unroll
        for (int nf = 0; nf < 2; ++nf)
            b[nf] = *(const bf16x8*)&Bs[wc * 32 + nf * 16 + lr][8 * lg];
#pragma unroll
        for (int mf = 0; mf < 4; ++mf)
#pragma unroll
            for (int nf = 0; nf < 2; ++nf)
                acc[mf][nf] = __builtin_amdgcn_mfma_f32_16x16x32_bf16(
                    a[mf], b[nf], acc[mf][nf], 0, 0, 0);
        __syncthreads();
    }
    if (mode == 0) {
#pragma unroll
        for (int mf = 0; mf < 4; ++mf)
#pragma unroll
            for (int reg = 0; reg < 4; ++reg) {
                int m = m0 + wr * 64 + mf * 16 + lg * 4 + reg;
#pragma unroll
                for (int nf = 0; nf < 2; ++nf) {
                    int c = n0 + wc * 32 + nf * 16 + lr;
                    float v = acc[mf][nf][reg] + bias[c];
                    Cb[(size_t)m * 256 + c] = f2bf(fmaxf(v, 0.f));
                }
            }
    } else {
#pragma unroll
        for (int mf = 0; mf < 4; ++mf)
#pragma unroll
            for (int reg = 0; reg < 4; ++reg) {
                int m = m0 + wr * 64 + mf * 16 + lg * 4 + reg;
                float w = sparse[m * 8 + ez];
                if (w != 0.f) {
                    int slot = (ez == i1[m]) ? 0 : 1;
                    float* dst = Ys + (size_t)slot * NN * 256 + (size_t)m * 256;
#pragma unroll
                    for (int nf = 0; nf < 2; ++nf) {
                        int c = n0 + wc * 32 + nf * 16 + lr;
                        dst[c] = w * (acc[mf][nf][reg] + bias[c]);
                    }
                }
            }
    }
}

// ------------------------------------------------------------- vo = z @ Wvo
__global__ __launch_bounds__(256) void k_vo(const _Float16* __restrict__ zh,
    const _Float16* __restrict__ zl, const float* __restrict__ Wvo,
    const float* __restrict__ bvo, float* __restrict__ vo)
{
    int n = blockIdx.x * 4 + (threadIdx.x >> 6);
    int lane = threadIdx.x & 63;
    float p[8];
#pragma unroll
    for (int e = 0; e < 8; ++e) p[e] = 0.f;
    for (int kk = lane; kk < ZK; kk += 64) {
        float zv = (float)zh[(size_t)n * ZK + kk] + (float)zl[(size_t)n * ZK + kk];
        float4 w0 = *(const float4*)&Wvo[kk * 8];
        float4 w1 = *(const float4*)&Wvo[kk * 8 + 4];
        p[0] = fmaf(zv, w0.x, p[0]); p[1] = fmaf(zv, w0.y, p[1]);
        p[2] = fmaf(zv, w0.z, p[2]); p[3] = fmaf(zv, w0.w, p[3]);
        p[4] = fmaf(zv, w1.x, p[4]); p[5] = fmaf(zv, w1.y, p[5]);
        p[6] = fmaf(zv, w1.z, p[6]); p[7] = fmaf(zv, w1.w, p[7]);
    }
#pragma unroll
    for (int msk = 1; msk <= 32; msk <<= 1)
#pragma unroll
        for (int e = 0; e < 8; ++e) p[e] += __shfl_xor(p[e], msk);
    if (lane == 0) {
#pragma unroll
        for (int e = 0; e < 8; ++e) vo[n * 8 + e] = p[e] + bvo[e];
    }
}

// ------------------- split-fp16 MFMA flash attention, swapped operands
// 512 thr, 8 waves x 32 rows (R11 structure, the 384.6us champion).
// KB=16 -> 2x16KB = 32KB LDS: tests whether the missing 2-block/CU
// co-residency was LDS-pool-limited (R11 used 64KB and stuck at 1 block).
// K staged via global_load_lds width=16; LDS linear, swizzle on the
// global source (rule #21).
__global__ __launch_bounds__(512, 2) void k_attn_mfma(
    const _Float16* __restrict__ qh_, const _Float16* __restrict__ ql_,
    const _Float16* __restrict__ kh, const _Float16* __restrict__ kl,
    const float* __restrict__ vo, float* __restrict__ pm,
    float* __restrict__ pl, float* __restrict__ pacc)
{
    __shared__ uint4 lds[2][KB * 64];   // per key: 512B hi | 512B lo (16B units)
    const int bid = blockIdx.x;
    const int split = bid & 15;
    const int rowblk = bid >> 4;
    const int n0 = rowblk * QB;
    const int t = threadIdx.x, w = t >> 6, lane = t & 63;
    const int g = lane >> 4, c = lane & 15;

    // Q B-fragments (col=lane&15=row, k=8*g + st*32), persistent in registers
    f16x8 bqh[2][8], bql[2][8];
#pragma unroll
    for (int rs = 0; rs < 2; ++rs) {
        const int row = n0 + w * 32 + rs * 16 + c;
#pragma unroll
        for (int st = 0; st < 8; ++st) {
            bqh[rs][st] = *(const f16x8*)&qh_[(size_t)row * 256 + st * 32 + g * 8];
            bql[rs][st] = *(const f16x8*)&ql_[(size_t)row * 256 + st * 32 + g * 8];
        }
    }
    float m_[2] = {-INFINITY, -INFINITY};
    float l_[2] = {0.f, 0.f};
    float pv[2][8];
#pragma unroll
    for (int rs = 0; rs < 2; ++rs)
#pragma unroll
        for (int e = 0; e < 8; ++e) pv[rs][e] = 0.f;

    const int kbase0 = split * (NN / ASPLIT);
    // Direct global->LDS staging (16 keys x 1KB). Linear LDS unit
    // u = i*512 + t: key=u>>6, half=(u>>5)&1, c16=(u&31)^(key&7).
    auto STAGE = [&](int buf, int kb) {
#pragma unroll
        for (int i = 0; i < 2; ++i) {
            int u = i * 512 + t;
            int key = u >> 6;
            int half = (u >> 5) & 1;
            int c16 = (u & 31) ^ (key & 7);      // pre-swizzled source
            const _Float16* src = half ? kl : kh;
            const _Float16* gp = src + (size_t)(kb + key) * 256 + c16 * 8;
            uint4* lp = &lds[buf][i * 512 + (t & ~63)];   // wave-uniform base
            __builtin_amdgcn_global_load_lds(
                (const __attribute__((address_space(1))) void*)gp,
                (__attribute__((address_space(3))) void*)lp, 16, 0, 0);
        }
    };
    STAGE(0, kbase0);
    __syncthreads();
    int cur = 0;
    const int NCH = (NN / ASPLIT) / KB;   // 32 chunks
    for (int ch = 0; ch < NCH; ++ch) {
        const int kbase = kbase0 + ch * KB;
        if (ch + 1 < NCH) STAGE(cur ^ 1, kbase + KB);   // async; rides vmcnt
        const char* kbp = (const char*)lds[cur] + c * 1024;
        const int swz = (c & 7) << 4;
        f32x4 acc0 = (f32x4){0.f, 0.f, 0.f, 0.f};
        f32x4 acc1 = (f32x4){0.f, 0.f, 0.f, 0.f};
        __builtin_amdgcn_s_setprio(1);
#pragma unroll
        for (int st = 0; st < 8; ++st) {
            const int off = (st * 64 + g * 16) ^ swz;
            f16x8 kah = *(const f16x8*)(kbp + off);
            f16x8 kal = *(const f16x8*)(kbp + 512 + off);
            acc0 = __builtin_amdgcn_mfma_f32_16x16x32_f16(kah, bqh[0][st], acc0, 0, 0, 0);
            acc0 = __builtin_amdgcn_mfma_f32_16x16x32_f16(kal, bqh[0][st], acc0, 0, 0, 0);
            acc0 = __builtin_amdgcn_mfma_f32_16x16x32_f16(kah, bql[0][st], acc0, 0, 0, 0);
            acc1 = __builtin_amdgcn_mfma_f32_16x16x32_f16(kah, bqh[1][st], acc1, 0, 0, 0);
            acc1 = __builtin_amdgcn_mfma_f32_16x16x32_f16(kal, bqh[1][st], acc1, 0, 0, 0);
            acc1 = __builtin_amdgcn_mfma_f32_16x16x32_f16(kah, bql[1][st], acc1, 0, 0, 0);
        }
        __builtin_amdgcn_s_setprio(0);
        // lane's keys this chunk: kb2 .. kb2+3
        const int kb2 = kbase + 4 * g;
        float4 w0[4], w1[4];
#pragma unroll
        for (int r = 0; r < 4; ++r) {
            w0[r] = *(const float4*)&vo[(kb2 + r) * 8];
            w1[r] = *(const float4*)&vo[(kb2 + r) * 8 + 4];
        }
#pragma unroll
        for (int rs = 0; rs < 2; ++rs) {
            f32x4 s = rs ? acc1 : acc0;
            float cm = fmaxf(fmaxf(s[0], s[1]), fmaxf(s[2], s[3]));
            float mn = fmaxf(m_[rs], cm);
            float rsc = __expf(m_[rs] - mn);
            float p0 = __expf(s[0] - mn);
            float p1 = __expf(s[1] - mn);
            float p2 = __expf(s[2] - mn);
            float p3 = __expf(s[3] - mn);
            l_[rs] = l_[rs] * rsc + (p0 + p1 + p2 + p3);
            m_[rs] = mn;
            pv[rs][0] = pv[rs][0]*rsc + p0*w0[0].x + p1*w0[1].x + p2*w0[2].x + p3*w0[3].x;
            pv[rs][1] = pv[rs][1]*rsc + p0*w0[0].y + p1*w0[1].y + p2*w0[2].y + p3*w0[3].y;
            pv[rs][2] = pv[rs][2]*rsc + p0*w0[0].z + p1*w0[1].z + p2*w0[2].z + p3*w0[3].z;
            pv[rs][3] = pv[rs][3]*rsc + p0*w0[0].w + p1*w0[1].w + p2*w0[2].w + p3*w0[3].w;
            pv[rs][4] = pv[rs][4]*rsc + p0*w1[0].x + p1*w1[1].x + p2*w1[2].x + p3*w1[3].x;
            pv[rs][5] = pv[rs][5]*rsc + p0*w1[0].y + p1*w1[1].y + p2*w1[2].y + p3*w1[3].y;
            pv[rs][6] = pv[rs][6]*rsc + p0*w1[0].z + p1*w1[1].z + p2*w1[2].z + p3*w1[3].z;
            pv[rs][7] = pv[rs][7]*rsc + p0*w1[0].w + p1*w1[1].w + p2*w1[2].w + p3*w1[3].w;
        }
        __syncthreads();
        cur ^= 1;
    }
    // --- merge across the 4 lanes (g=0..3) sharing each q-row ---
#pragma unroll
    for (int msk = 16; msk <= 32; msk <<= 1) {
#pragma unroll
        for (int rs = 0; rs < 2; ++rs) {
            float mo = __shfl_xor(m_[rs], msk);
            float lo = __shfl_xor(l_[rs], msk);
            float mn = fmaxf(m_[rs], mo);
            float a = __expf(m_[rs] - mn), b = __expf(mo - mn);
            l_[rs] = l_[rs] * a + lo * b;
#pragma unroll
            for (int e = 0; e < 8; ++e) {
                float po = __shfl_xor(pv[rs][e], msk);
                pv[rs][e] = pv[rs][e] * a + po * b;
            }
            m_[rs] = mn;
        }
    }
    if (g == 0) {
#pragma unroll
        for (int rs = 0; rs < 2; ++rs) {
            int n = n0 + w * 32 + rs * 16 + c;
            pm[split * NN + n] = m_[rs];
            pl[split * NN + n] = l_[rs];
#pragma unroll
            for (int e = 0; e < 8; ++e)
                pacc[(size_t)split * NN * 8 + n * 8 + e] = pv[rs][e];
        }
    }
}

// ----------------------------------- merge split-K partials -> top2 weights
__global__ __launch_bounds__(256) void k_attn_merge(
    const float* __restrict__ pm, const float* __restrict__ pl,
    const float* __restrict__ pacc, const float* __restrict__ outb,
    float* __restrict__ sparse, int* __restrict__ i1o)
{
    int n = blockIdx.x * 256 + threadIdx.x;
    float mn = -INFINITY;
#pragma unroll
    for (int s = 0; s < ASPLIT; ++s) mn = fmaxf(mn, pm[s * NN + n]);
    float l = 0.f;
    float lg[8];
#pragma unroll
    for (int e = 0; e < 8; ++e) lg[e] = 0.f;
#pragma unroll
    for (int s = 0; s < ASPLIT; ++s) {
        float r = __expf(pm[s * NN + n] - mn);
        l += pl[s * NN + n] * r;
#pragma unroll
        for (int e = 0; e < 8; ++e)
            lg[e] += pacc[(size_t)s * NN * 8 + n * 8 + e] * r;
    }
    float inv = 1.f / l;
#pragma unroll
    for (int e = 0; e < 8; ++e) lg[e] = lg[e] * inv + outb[e];
    int i1 = 0; float v1 = lg[0];
#pragma unroll
    for (int e = 1; e < 8; ++e) if (lg[e] > v1) { v1 = lg[e]; i1 = e; }
    int i2 = -1; float v2 = -INFINITY;
#pragma unroll
    for (int e = 0; e < 8; ++e) if (e != i1 && lg[e] > v2) { v2 = lg[e]; i2 = e; }
    float e2 = __expf(v2 - v1);
    float w1 = 1.f / (1.f + e2);
    float w2 = e2 / (1.f + e2);
#pragma unroll
    for (int e = 0; e < 8; ++e)
        sparse[n * 8 + e] = (e == i1) ? w1 : ((e == i2) ? w2 : 0.f);
    i1o[n] = i1;
}

// ------------------- bf16 gather-mean: X = bf16(src + neigh_mean(src))
// 1-D grid: expert = bid & ((1<<eshift)-1) (XCD-pinned), node-blk = bid>>eshift
// 4-way unrolled gather: 4 row-loads in flight, 4 independent accumulators.
__global__ __launch_bounds__(256) void k_agg_b2b(
    const unsigned short* __restrict__ HeAll, const int* __restrict__ rowptr,
    const int* __restrict__ colidx, unsigned short* __restrict__ XAll,
    int eshift)
{
    const int bid = blockIdx.x;
    const int e = bid & ((1 << eshift) - 1);
    const int nb = bid >> eshift;
    const unsigned short* He = HeAll + (size_t)e * NN * 256;
    unsigned short* X = XAll + (size_t)e * NN * 256;
    int n = nb * 4 + (threadIdx.x >> 6);
    int c4 = (threadIdx.x & 63) * 4;
    int r0 = rowptr[n], r1 = rowptr[n + 1];
    float a0 = 0.f, a1 = 0.f, a2 = 0.f, a3 = 0.f;
    float b0 = 0.f, b1 = 0.f, b2 = 0.f, b3 = 0.f;
    float e0 = 0.f, e1 = 0.f, e2 = 0.f, e3 = 0.f;
    float d0 = 0.f, d1 = 0.f, d2 = 0.f, d3 = 0.f;
    int i = r0;
    for (; i + 4 <= r1; i += 4) {
        int s0 = colidx[i], s1 = colidx[i + 1], s2 = colidx[i + 2], s3 = colidx[i + 3];
        ushort4 v0 = *(const ushort4*)&He[(size_t)s0 * 256 + c4];
        ushort4 v1 = *(const ushort4*)&He[(size_t)s1 * 256 + c4];
        ushort4 v2 = *(const ushort4*)&He[(size_t)s2 * 256 + c4];
        ushort4 v3 = *(const ushort4*)&He[(size_t)s3 * 256 + c4];
        a0 += b2f(v0.x); a1 += b2f(v0.y); a2 += b2f(v0.z); a3 += b2f(v0.w);
        b0 += b2f(v1.x); b1 += b2f(v1.y); b2 += b2f(v1.z); b3 += b2f(v1.w);
        e0 += b2f(v2.x); e1 += b2f(v2.y); e2 += b2f(v2.z); e3 += b2f(v2.w);
        d0 += b2f(v3.x); d1 += b2f(v3.y); d2 += b2f(v3.z); d3 += b2f(v3.w);
    }
    for (; i < r1; ++i) {
        int sn = colidx[i];
        ushort4 v = *(const ushort4*)&He[(size_t)sn * 256 + c4];
        a0 += b2f(v.x); a1 += b2f(v.y); a2 += b2f(v.z); a3 += b2f(v.w);
    }
    a0 += b0 + e0 + d0; a1 += b1 + e1 + d1;
    a2 += b2 + e2 + d2; a3 += b3 + e3 + d3;
    int deg = r1 - r0;
    float inv = 1.f / (float)(deg > 1 ? deg : 1);
    ushort4 self = *(const ushort4*)&He[(size_t)n * 256 + c4];
    ushort4 o;
    o.x = f2bf(b2f(self.x) + a0 * inv); o.y = f2bf(b2f(self.y) + a1 * inv);
    o.z = f2bf(b2f(self.z) + a2 * inv); o.w = f2bf(b2f(self.w) + a3 * inv);
    *(ushort4*)&X[(size_t)n * 256 + c4] = o;
}

// ------------------------------------------------ out = Ys[0] + Ys[1]
__global__ __launch_bounds__(256) void k_combine2(const float* __restrict__ Ys,
                                                  float* __restrict__ out)
{
    int i = (blockIdx.x * 256 + threadIdx.x) * 4;
    float4 a = *(const float4*)&Ys[i];
    float4 b = *(const float4*)&Ys[(size_t)NN * 256 + i];
    float4 o;
    o.x = a.x + b.x; o.y = a.y + b.y; o.z = a.z + b.z; o.w = a.w + b.w;
    *(float4*)&out[i] = o;
}

// ==========================================================================
extern "C" void kernel_launch(void* const* d_in, const int* in_sizes, int n_in,
                              void* d_out, int out_size, void* d_ws, size_t ws_size,
                              hipStream_t stream)
{
    (void)n_in; (void)out_size;
    const float* x     = (const float*)d_in[0];
    const int*   ei    = (const int*)d_in[1];
    const int*   batch = (const int*)d_in[2];
    const float* encW  = (const float*)d_in[3];
    const float* encb  = (const float*)d_in[4];
    const float* qW    = (const float*)d_in[5];
    const float* qb    = (const float*)d_in[6];
    const float* kW    = (const float*)d_in[7];
    const float* kb    = (const float*)d_in[8];
    const float* vW    = (const float*)d_in[9];
    const float* vb    = (const float*)d_in[10];
    const float* outW  = (const float*)d_in[11];
    const float* outb  = (const float*)d_in[12];
    const float* eWh   = (const float*)d_in[13];
    const float* ebh   = (const float*)d_in[14];
    const float* eWo   = (const float*)d_in[15];
    const float* ebo   = (const float*)d_in[16];
    float* out = (float*)d_out;
    if (in_sizes[0] != NN * 6 || in_sizes[1] != 2 * NE) return;

    char* wsp = (char*)d_ws;
    size_t off = 0;
    auto alloc = [&](size_t bytes) -> void* {
        void* p = wsp + off;
        off += (bytes + 511) & ~(size_t)511;
        return p;
    };
    _Float16* zh = (_Float16*)alloc((size_t)NN * ZK * 2);
    _Float16* zl = (_Float16*)alloc((size_t)NN * ZK * 2);
    unsigned short* zb = (unsigned short*)alloc((size_t)NN * 256 * 2);
    // 16MB block: q/k split-fp16; reused as Ys (2 x NN x 256 fp32) after attn
    _Float16* qh = (_Float16*)alloc((size_t)4 * NN * 256 * 2);
    _Float16* ql = qh + (size_t)NN * 256;
    _Float16* kh = ql + (size_t)NN * 256;
    _Float16* kl = kh + (size_t)NN * 256;
    float* Ys = (float*)qh;
    float* vo     = (float*)alloc((size_t)NN * 8 * 4);
    float* sparse = (float*)alloc((size_t)NN * 8 * 4);
    int*   i1buf  = (int*)alloc((size_t)NN * 4);
    unsigned short* Xball = (unsigned short*)alloc((size_t)8 * NN * 256 * 2);
    unsigned short* Heb   = (unsigned short*)alloc((size_t)8 * NN * 256 * 2);
    unsigned short* Bth   = (unsigned short*)alloc((size_t)16 * 65536 * 2);
    unsigned short* Bto   = (unsigned short*)alloc((size_t)8 * 65536 * 2);
    _Float16* Wth = (_Float16*)alloc((size_t)2 * 256 * ZK * 2);
    _Float16* Wtl = (_Float16*)alloc((size_t)2 * 256 * ZK * 2);
    float* Wvo  = (float*)alloc((size_t)ZK * 8 * 4);
    float* bvo  = (float*)alloc(8 * 4);
    float* pm   = (float*)alloc((size_t)ASPLIT * NN * 4);
    float* plb  = (float*)alloc((size_t)ASPLIT * NN * 4);
    float* pacc = (float*)alloc((size_t)ASPLIT * NN * 8 * 4);
    int* ints   = (int*)alloc((size_t)(NG + NG + NN + NN) * 4);
    int* ncnt = ints, *ecnt = ints + NG, *indeg = ecnt + NG, *cursor = indeg + NN;
    int* rowptr = (int*)alloc((size_t)(NN + 1) * 4);
    int* colidx = (int*)alloc((size_t)NE * 4);
    if (off > ws_size) return;

    hipMemsetAsync(ints, 0, (size_t)(NG + NG + NN + NN) * 4, stream);
    k_counts<<<64, 256, 0, stream>>>(ei, batch, ncnt, ecnt, indeg);
    k_prep_qkw<<<(2 * 256 * ZK) / 256, 256, 0, stream>>>(qW, kW, Wth, Wtl);
    k_prep_vo<<<(ZK * 8 + 8 + 255) / 256, 256, 0, stream>>>(vW, vb, outW, Wvo, bvo);
    k_prep_w<<<(24 * 65536) / 256, 256, 0, stream>>>(eWh, eWo, Bth, Bto);
    k_encoder<<<NN, 256, 0, stream>>>(x, encW, encb, batch, ncnt, ecnt, zh, zl, zb);
    k_scan<<<1, 256, 0, stream>>>(indeg, rowptr);
    k_fill<<<(NE + 255) / 256, 256, 0, stream>>>(ei, rowptr, cursor, colidx);

    float scale = 1.f / sqrtf(258.f);
    k_gemm_qk<<<256, 512, 0, stream>>>(zh, zl, Wth, Wtl, qb, kb,
                                       qh, ql, kh, kl, scale);
    k_vo<<<NN / 4, 256, 0, stream>>>(zh, zl, Wvo, bvo, vo);

    k_attn_mfma<<<(NN / QB) * ASPLIT, 512, 0, stream>>>(qh, ql, kh, kl, vo, pm, plb, pacc);
    k_attn_merge<<<NN / 256, 256, 0, stream>>>(pm, plb, pacc, outb, sparse, i1buf);

    // ---- experts: 3 batched agg + 3 batched MFMA GEMMs + combine ----
    k_agg_b2b<<<NN / 4, 256, 0, stream>>>(zb, rowptr, colidx, Xball, 0);  // slot 0
    // layer 1: shared A (Xball slot 0)
    k_gemm_bf<<<1024, 512, 0, stream>>>(Xball, Bth, ebh, Heb, nullptr, nullptr, nullptr,
                                        0, (long long)2 * 65536, (long long)NN * 256,
                                        2 * 256, 0);
    // layer 2
    k_agg_b2b<<<(NN / 4) * 8, 256, 0, stream>>>(Heb, rowptr, colidx, Xball, 3);
    k_gemm_bf<<<1024, 512, 0, stream>>>(Xball, Bth + 65536, ebh + 256, Heb,
                                        nullptr, nullptr, nullptr,
                                        (long long)NN * 256, (long long)2 * 65536,
                                        (long long)NN * 256, 2 * 256, 0);
    // layer 3 -> top-2 slot buffers
    k_agg_b2b<<<(NN / 4) * 8, 256, 0, stream>>>(Heb, rowptr, colidx, Xball, 3);
    k_gemm_bf<<<1024, 512, 0, stream>>>(Xball, Bto, ebo, nullptr, Ys, sparse, i1buf,
                                        (long long)NN * 256, (long long)65536,
                                        0, 256, 1);
    k_combine2<<<(NN * 256 / 4) / 256, 256, 0, stream>>>(Ys, out);
}

// Round 15
// 384.456 us; speedup vs baseline: 2.5593x; 1.0229x over previous
//
#include <hip/hip_runtime.h>
#include <math.h>

#define NN 8192      // nodes
#define NE 131072    // edges
#define ZK 288       // padded z width (258 -> 288, multiple of 32)
#define NG 64        // graphs
#define ASPLIT 16    // attention split-K (split = bid&15)
#define QB 256       // q-rows per attention block (8 waves x 32)
#define KB 32        // keys per attention chunk

typedef __attribute__((ext_vector_type(8))) short bf16x8;
typedef __attribute__((ext_vector_type(4))) float f32x4;
typedef __attribute__((ext_vector_type(8))) _Float16 f16x8;
typedef __attribute__((ext_vector_type(4))) _Float16 f16x4;

static __device__ __forceinline__ unsigned short f2bf(float f) {
    unsigned u = __float_as_uint(f);
    unsigned r = (u + 0x7FFFu + ((u >> 16) & 1u)) >> 16;   // RNE
    return (unsigned short)r;
}
static __device__ __forceinline__ float b2f(unsigned short h) {
    return __uint_as_float(((unsigned)h) << 16);
}

// ------------------------- counts via per-block LDS histograms (G12)
__global__ __launch_bounds__(256) void k_counts(const int* __restrict__ ei,
    const int* __restrict__ batch, int* ncnt, int* ecnt, int* indeg)
{
    __shared__ int he[NG], hn[NG];
    const int t = threadIdx.x, b = blockIdx.x;
    if (t < NG) { he[t] = 0; hn[t] = 0; }
    __syncthreads();
    const int e0 = b * (NE / 64);
#pragma unroll
    for (int i = 0; i < (NE / 64) / 256; ++i) {
        int idx = e0 + i * 256 + t;
        int src = ei[idx], dst = ei[NE + idx];
        atomicAdd(&he[batch[src]], 1);
        atomicAdd(&indeg[dst], 1);
    }
    if (t < 128) atomicAdd(&hn[batch[b * 128 + t]], 1);
    __syncthreads();
    if (t < NG) {
        if (he[t]) atomicAdd(&ecnt[t], he[t]);
        if (hn[t]) atomicAdd(&ncnt[t], hn[t]);
    }
}

// -------- encoder + size feats -> zh/zl (split-fp16, ZK) and zb (bf16, 256)
__global__ __launch_bounds__(256) void k_encoder(const float* __restrict__ x,
    const float* __restrict__ encW, const float* __restrict__ encb,
    const int* __restrict__ batch, const int* __restrict__ ncnt,
    const int* __restrict__ ecnt, _Float16* __restrict__ zh,
    _Float16* __restrict__ zl, unsigned short* __restrict__ zb)
{
    int n = blockIdx.x, c = threadIdx.x;
    __shared__ float xr[8];
    if (c < 6) xr[c] = x[n * 6 + c];
    __syncthreads();
    float a = encb[c];
#pragma unroll
    for (int i = 0; i < 6; ++i) a = fmaf(xr[i], encW[i * 256 + c], a);
    float h = fmaxf(a, 0.f);
    _Float16 hi = (_Float16)h;
    zh[(size_t)n * ZK + c] = hi;
    zl[(size_t)n * ZK + c] = (_Float16)(h - (float)hi);
    zb[n * 256 + c] = f2bf(h);
    if (c == 0) {
        int g = batch[n];
        float s0 = log1pf((float)ncnt[g]);
        float s1 = log1pf((float)ecnt[g]);
        _Float16 h0 = (_Float16)s0, h1 = (_Float16)s1;
        zh[(size_t)n * ZK + 256] = h0;
        zl[(size_t)n * ZK + 256] = (_Float16)(s0 - (float)h0);
        zh[(size_t)n * ZK + 257] = h1;
        zl[(size_t)n * ZK + 257] = (_Float16)(s1 - (float)h1);
    }
    if (c >= 2 && c < 32) {                       // zero pad 258..287
        zh[(size_t)n * ZK + 256 + c] = (_Float16)0.f;
        zl[(size_t)n * ZK + 256 + c] = (_Float16)0.f;
    }
}

// ---------------------------------------------------------------- CSR build
__global__ __launch_bounds__(256) void k_scan(const int* __restrict__ indeg,
                                              int* __restrict__ rowptr)
{
    __shared__ int part[256];
    int t = threadIdx.x;
    int base = t * 32, s = 0;
    for (int i = 0; i < 32; ++i) s += indeg[base + i];
    part[t] = s;
    __syncthreads();
    if (t == 0) {
        int run = 0;
        for (int i = 0; i < 256; ++i) { int v = part[i]; part[i] = run; run += v; }
        rowptr[NN] = run;
    }
    __syncthreads();
    int run = part[t];
    for (int i = 0; i < 32; ++i) { rowptr[base + i] = run; run += indeg[base + i]; }
}

__global__ __launch_bounds__(256) void k_fill(const int* __restrict__ ei,
    const int* __restrict__ rowptr, int* __restrict__ cursor, int* __restrict__ colidx)
{
    int tid = blockIdx.x * 256 + threadIdx.x;
    if (tid >= NE) return;
    int dst = ei[NE + tid];
    int pos = atomicAdd(&cursor[dst], 1);
    colidx[rowptr[dst] + pos] = ei[tid];
}

// ---------------- Wq/Wk -> split-fp16, transposed [sel][out=256][in=288]
__global__ __launch_bounds__(256) void k_prep_qkw(const float* __restrict__ qW,
    const float* __restrict__ kW, _Float16* __restrict__ Wth,
    _Float16* __restrict__ Wtl)
{
    int idx = blockIdx.x * 256 + threadIdx.x;     // 2*256*288 = 147456
    int r = idx % ZK;
    int c = (idx / ZK) & 255;
    int sel = idx / (ZK * 256);
    const float* W = sel ? kW : qW;
    float w = (r < 258) ? W[r * 256 + c] : 0.f;
    _Float16 hi = (_Float16)w;
    Wth[idx] = hi;
    Wtl[idx] = (_Float16)(w - (float)hi);
}

// W_vo = v_W @ out_W (padded to ZK rows), bvo = v_b @ out_W
__global__ __launch_bounds__(256) void k_prep_vo(const float* __restrict__ vW,
    const float* __restrict__ vb, const float* __restrict__ outW,
    float* __restrict__ Wvo, float* __restrict__ bvo)
{
    int idx = blockIdx.x * 256 + threadIdx.x;
    if (idx < ZK * 8) {
        int r = idx >> 3, e = idx & 7;
        float s = 0.f;
        if (r < 258)
            for (int c = 0; c < 256; ++c) s = fmaf(vW[r * 256 + c], outW[c * 8 + e], s);
        Wvo[idx] = s;
    } else if (idx < ZK * 8 + 8) {
        int e = idx - ZK * 8;
        float s = 0.f;
        for (int c = 0; c < 256; ++c) s = fmaf(vb[c], outW[c * 8 + e], s);
        bvo[e] = s;
    }
}

// expert weights -> bf16, transposed to [out][in] so B-frags load contiguous
__global__ __launch_bounds__(256) void k_prep_w(const float* __restrict__ eWh,
    const float* __restrict__ eWo, unsigned short* __restrict__ Bth,
    unsigned short* __restrict__ Bto)
{
    int id = blockIdx.x * 256 + threadIdx.x;
    if (id < 16 * 65536) {
        int h = id & 255, kcol = (id >> 8) & 255, m = id >> 16;  // m = e*2+l
        Bth[id] = f2bf(eWh[((size_t)m * 256 + h) * 256 + kcol]);
    } else if (id < 24 * 65536) {
        int j = id - 16 * 65536;
        int h = j & 255, o = (j >> 8) & 255, e = j >> 16;
        Bto[j] = f2bf(eWo[((size_t)e * 256 + h) * 256 + o]);
    }
}

// -------- split-fp16 MFMA GEMM for q/k: C = (z @ W + bias) * scl -> (hi,lo)
// 128x128 tile, 512 thr (8 waves 2x4), K=288 in 9 steps of 32.
// acc = Ah*Bh + Ah*Bl + Al*Bh (fp32 MFMA accum).
// 1-D grid: sel = bid&1 (q/k), tile = bid>>1 (2 n-tiles x 64 m-tiles).
__global__ __launch_bounds__(512) void k_gemm_qk(
    const _Float16* __restrict__ zh, const _Float16* __restrict__ zl,
    const _Float16* __restrict__ Wth, const _Float16* __restrict__ Wtl,
    const float* __restrict__ qb, const float* __restrict__ kb,
    _Float16* __restrict__ qho, _Float16* __restrict__ qlo,
    _Float16* __restrict__ kho, _Float16* __restrict__ klo, float scale)
{
    const int bid = blockIdx.x;
    const int sel = bid & 1;
    const int tile = bid >> 1;
    const int n0 = (tile & 1) * 128, m0 = (tile >> 1) * 128;
    const _Float16* Bh = Wth + (size_t)sel * 256 * ZK;
    const _Float16* Bl = Wtl + (size_t)sel * 256 * ZK;
    const float* bias = sel ? kb : qb;
    _Float16* Ch = sel ? kho : qho;
    _Float16* Cl = sel ? klo : qlo;
    const float scl = sel ? 1.0f : scale;
    __shared__ _Float16 Ash[128][40], Asl[128][40];
    __shared__ _Float16 Bsh[128][40], Bsl[128][40];
    const int t = threadIdx.x;
    const int wid = t >> 6, lane = t & 63;
    const int wr = wid >> 2, wc = wid & 3;
    const int lr = lane & 15, lg = lane >> 4;
    f32x4 acc[4][2];
#pragma unroll
    for (int mf = 0; mf < 4; ++mf)
#pragma unroll
        for (int nf = 0; nf < 2; ++nf) acc[mf][nf] = (f32x4){0.f, 0.f, 0.f, 0.f};

    const int rA = t >> 2, cA = t & 3;
    for (int k0 = 0; k0 < ZK; k0 += 32) {
        *(uint4*)&Ash[rA][8 * cA] = *(const uint4*)&zh[(size_t)(m0 + rA) * ZK + k0 + 8 * cA];
        *(uint4*)&Asl[rA][8 * cA] = *(const uint4*)&zl[(size_t)(m0 + rA) * ZK + k0 + 8 * cA];
        *(uint4*)&Bsh[rA][8 * cA] = *(const uint4*)&Bh[(size_t)(n0 + rA) * ZK + k0 + 8 * cA];
        *(uint4*)&Bsl[rA][8 * cA] = *(const uint4*)&Bl[(size_t)(n0 + rA) * ZK + k0 + 8 * cA];
        __syncthreads();
        f16x8 ah[4], al[4], bh[2], bl[2];
#pragma unroll
        for (int mf = 0; mf < 4; ++mf) {
            ah[mf] = *(const f16x8*)&Ash[wr * 64 + mf * 16 + lr][8 * lg];
            al[mf] = *(const f16x8*)&Asl[wr * 64 + mf * 16 + lr][8 * lg];
        }
#pragma unroll
        for (int nf = 0; nf < 2; ++nf) {
            bh[nf] = *(const f16x8*)&Bsh[wc * 32 + nf * 16 + lr][8 * lg];
            bl[nf] = *(const f16x8*)&Bsl[wc * 32 + nf * 16 + lr][8 * lg];
        }
#pragma unroll
        for (int mf = 0; mf < 4; ++mf)
#pragma unroll
            for (int nf = 0; nf < 2; ++nf) {
                acc[mf][nf] = __builtin_amdgcn_mfma_f32_16x16x32_f16(ah[mf], bh[nf], acc[mf][nf], 0, 0, 0);
                acc[mf][nf] = __builtin_amdgcn_mfma_f32_16x16x32_f16(ah[mf], bl[nf], acc[mf][nf], 0, 0, 0);
                acc[mf][nf] = __builtin_amdgcn_mfma_f32_16x16x32_f16(al[mf], bh[nf], acc[mf][nf], 0, 0, 0);
            }
        __syncthreads();
    }
#pragma unroll
    for (int mf = 0; mf < 4; ++mf)
#pragma unroll
        for (int reg = 0; reg < 4; ++reg) {
            int m = m0 + wr * 64 + mf * 16 + lg * 4 + reg;
#pragma unroll
            for (int nf = 0; nf < 2; ++nf) {
                int c = n0 + wc * 32 + nf * 16 + lr;
                float v = (acc[mf][nf][reg] + bias[c]) * scl;
                _Float16 hi = (_Float16)v;
                Ch[(size_t)m * 256 + c] = hi;
                Cl[(size_t)m * 256 + c] = (_Float16)(v - (float)hi);
            }
        }
}

// ----------------------------------------------------- bf16 MFMA GEMM
// 128x128 tile, 512 thr (8 waves as 2x4), BK=32, 16x16x32 MFMA.
// 1-D grid: expert = bid&7 (XCD-pinned), tile = bid>>3 (2 n-tiles, 64 m-tiles)
// mode 0: relu -> bf16 Cb.  mode 1: Ys[slot] = w*(acc+bias) (top-2 slots).
__global__ __launch_bounds__(512) void k_gemm_bf(
    const unsigned short* __restrict__ A,
    const unsigned short* __restrict__ Bt,
    const float* __restrict__ bias,
    unsigned short* __restrict__ Cb,
    float* __restrict__ Ys,
    const float* __restrict__ sparse,
    const int* __restrict__ i1,
    long long aStrideZ, long long btStrideZ, long long cStrideZ, int biasStrideZ,
    int mode)
{
    const int bid = blockIdx.x;
    const int ez = bid & 7;
    const int tile = bid >> 3;
    const int n0 = (tile & 1) * 128, m0 = (tile >> 1) * 128;
    A    += (size_t)ez * aStrideZ;
    Bt   += (size_t)ez * btStrideZ;
    bias += (size_t)ez * biasStrideZ;
    if (mode == 0) Cb += (size_t)ez * cStrideZ;
    __shared__ unsigned short As[128][40];
    __shared__ unsigned short Bs[128][40];
    const int t = threadIdx.x;
    const int wid = t >> 6, lane = t & 63;
    const int wr = wid >> 2, wc = wid & 3;       // 2x4 waves: 64x32 per wave
    const int lr = lane & 15, lg = lane >> 4;
    f32x4 acc[4][2];
#pragma unroll
    for (int mf = 0; mf < 4; ++mf)
#pragma unroll
        for (int nf = 0; nf < 2; ++nf) acc[mf][nf] = (f32x4){0.f, 0.f, 0.f, 0.f};

    const int rA = t >> 2, cA = t & 3;           // 128 rows x 4 col-chunks
    for (int k0 = 0; k0 < 256; k0 += 32) {
        uint4 va = *(const uint4*)&A[(size_t)(m0 + rA) * 256 + k0 + 8 * cA];
        uint4 vB = *(const uint4*)&Bt[(size_t)(n0 + rA) * 256 + k0 + 8 * cA];
        *(uint4*)&As[rA][8 * cA] = va;
        *(uint4*)&Bs[rA][8 * cA] = vB;
        __syncthreads();
        bf16x8 a[4], b[2];
#pragma unroll
        for (int mf = 0; mf < 4; ++mf)
            a[mf] = *(const bf16x8*)&As[wr * 64 + mf * 16 + lr][8 * lg];
#pragma unroll
        for (int nf = 0; nf < 2; ++nf)
            b[nf] = *(const bf16x8*)&Bs[wc * 32 + nf * 16 + lr][8 * lg];
#pragma unroll
        for (int mf = 0; mf < 4; ++mf)
#pragma unroll
            for (int nf = 0; nf < 2; ++nf)
                acc[mf][nf] = __builtin_amdgcn_mfma_f32_16x16x32_bf16(
                    a[mf], b[nf], acc[mf][nf], 0, 0, 0);
        __syncthreads();
    }
    if (mode == 0) {
#pragma unroll
        for (int mf = 0; mf < 4; ++mf)
#pragma unroll
            for (int reg = 0; reg < 4; ++reg) {
                int m = m0 + wr * 64 + mf * 16 + lg * 4 + reg;
#pragma unroll
                for (int nf = 0; nf < 2; ++nf) {
                    int c = n0 + wc * 32 + nf * 16 + lr;
                    float v = acc[mf][nf][reg] + bias[c];
                    Cb[(size_t)m * 256 + c] = f2bf(fmaxf(v, 0.f));
                }
            }
    } else {
#pragma unroll
        for (int mf = 0; mf < 4; ++mf)
#pragma unroll
            for (int reg = 0; reg < 4; ++reg) {
                int m = m0 + wr * 64 + mf * 16 + lg * 4 + reg;
                float w = sparse[m * 8 + ez];
                if (w != 0.f) {
                    int slot = (ez == i1[m]) ? 0 : 1;
                    float* dst = Ys + (size_t)slot * NN * 256 + (size_t)m * 256;
#pragma unroll
                    for (int nf = 0; nf < 2; ++nf) {
                        int c = n0 + wc * 32 + nf * 16 + lr;
                        dst[c] = w * (acc[mf][nf][reg] + bias[c]);
                    }
                }
            }
    }
}

// ------------------------------------------------------------- vo = z @ Wvo
__global__ __launch_bounds__(256) void k_vo(const _Float16* __restrict__ zh,
    const _Float16* __restrict__ zl, const float* __restrict__ Wvo,
    const float* __restrict__ bvo, float* __restrict__ vo)
{
    int n = blockIdx.x * 4 + (threadIdx.x >> 6);
    int lane = threadIdx.x & 63;
    float p[8];
#pragma unroll
    for (int e = 0; e < 8; ++e) p[e] = 0.f;
    for (int kk = lane; kk < ZK; kk += 64) {
        float zv = (float)zh[(size_t)n * ZK + kk] + (float)zl[(size_t)n * ZK + kk];
        float4 w0 = *(const float4*)&Wvo[kk * 8];
        float4 w1 = *(const float4*)&Wvo[kk * 8 + 4];
        p[0] = fmaf(zv, w0.x, p[0]); p[1] = fmaf(zv, w0.y, p[1]);
        p[2] = fmaf(zv, w0.z, p[2]); p[3] = fmaf(zv, w0.w, p[3]);
        p[4] = fmaf(zv, w1.x, p[4]); p[5] = fmaf(zv, w1.y, p[5]);
        p[6] = fmaf(zv, w1.z, p[6]); p[7] = fmaf(zv, w1.w, p[7]);
    }
#pragma unroll
    for (int msk = 1; msk <= 32; msk <<= 1)
#pragma unroll
        for (int e = 0; e < 8; ++e) p[e] += __shfl_xor(p[e], msk);
    if (lane == 0) {
#pragma unroll
        for (int e = 0; e < 8; ++e) vo[n * 8 + e] = p[e] + bvo[e];
    }
}

// ------------------- split-fp16 MFMA flash attention, swapped operands
// R11 champion config: 512 thr, 8 waves x 32 rows, KB=32 (64KB LDS).
// A = K from LDS, B = Q in regs. K staged via global_load_lds width=16
// (zero staging VGPRs, async across MFMA phase); LDS linear, XOR swizzle
// applied to per-lane GLOBAL source (rule #21). Measured floor: the
// serialized pipe sum (MFMA 53 + LDS 41 + VALU ~30 us); occupancy is
// pinned at ~8 waves/CU regardless of LDS/VGPR config (R12-R14 sweeps).
__global__ __launch_bounds__(512, 2) void k_attn_mfma(
    const _Float16* __restrict__ qh_, const _Float16* __restrict__ ql_,
    const _Float16* __restrict__ kh, const _Float16* __restrict__ kl,
    const float* __restrict__ vo, float* __restrict__ pm,
    float* __restrict__ pl, float* __restrict__ pacc)
{
    __shared__ uint4 lds[2][KB * 64];   // per key: 512B hi | 512B lo (16B units)
    const int bid = blockIdx.x;
    const int split = bid & 15;
    const int rowblk = bid >> 4;
    const int n0 = rowblk * QB;
    const int t = threadIdx.x, w = t >> 6, lane = t & 63;
    const int g = lane >> 4, c = lane & 15;

    // Q B-fragments (col=lane&15=row, k=8*g + st*32), persistent in registers
    f16x8 bqh[2][8], bql[2][8];
#pragma unroll
    for (int rs = 0; rs < 2; ++rs) {
        const int row = n0 + w * 32 + rs * 16 + c;
#pragma unroll
        for (int st = 0; st < 8; ++st) {
            bqh[rs][st] = *(const f16x8*)&qh_[(size_t)row * 256 + st * 32 + g * 8];
            bql[rs][st] = *(const f16x8*)&ql_[(size_t)row * 256 + st * 32 + g * 8];
        }
    }
    float m_[2] = {-INFINITY, -INFINITY};
    float l_[2] = {0.f, 0.f};
    float pv[2][8];
#pragma unroll
    for (int rs = 0; rs < 2; ++rs)
#pragma unroll
        for (int e = 0; e < 8; ++e) pv[rs][e] = 0.f;

    const int kbase0 = split * (NN / ASPLIT);
    auto STAGE = [&](int buf, int kb) {
#pragma unroll
        for (int i = 0; i < 4; ++i) {
            int u = i * 512 + t;
            int key = u >> 6;
            int half = (u >> 5) & 1;
            int c16 = (u & 31) ^ (key & 7);      // pre-swizzled source
            const _Float16* src = half ? kl : kh;
            const _Float16* gp = src + (size_t)(kb + key) * 256 + c16 * 8;
            uint4* lp = &lds[buf][i * 512 + (t & ~63)];   // wave-uniform base
            __builtin_amdgcn_global_load_lds(
                (const __attribute__((address_space(1))) void*)gp,
                (__attribute__((address_space(3))) void*)lp, 16, 0, 0);
        }
    };
    STAGE(0, kbase0);
    __syncthreads();
    int cur = 0;
    const int NCH = (NN / ASPLIT) / KB;   // 16 chunks
    for (int ch = 0; ch < NCH; ++ch) {
        const int kbase = kbase0 + ch * KB;
        if (ch + 1 < NCH) STAGE(cur ^ 1, kbase + KB);   // async; rides vmcnt
#pragma unroll
        for (int kt = 0; kt < 2; ++kt) {
            const char* kbp = (const char*)lds[cur] + (kt * 16 + c) * 1024;
            const int swz = ((kt * 16 + c) & 7) << 4;
            f32x4 acc0 = (f32x4){0.f, 0.f, 0.f, 0.f};
            f32x4 acc1 = (f32x4){0.f, 0.f, 0.f, 0.f};
            __builtin_amdgcn_s_setprio(1);
#pragma unroll
            for (int st = 0; st < 8; ++st) {
                const int off = (st * 64 + g * 16) ^ swz;
                f16x8 kah = *(const f16x8*)(kbp + off);
                f16x8 kal = *(const f16x8*)(kbp + 512 + off);
                acc0 = __builtin_amdgcn_mfma_f32_16x16x32_f16(kah, bqh[0][st], acc0, 0, 0, 0);
                acc0 = __builtin_amdgcn_mfma_f32_16x16x32_f16(kal, bqh[0][st], acc0, 0, 0, 0);
                acc0 = __builtin_amdgcn_mfma_f32_16x16x32_f16(kah, bql[0][st], acc0, 0, 0, 0);
                acc1 = __builtin_amdgcn_mfma_f32_16x16x32_f16(kah, bqh[1][st], acc1, 0, 0, 0);
                acc1 = __builtin_amdgcn_mfma_f32_16x16x32_f16(kal, bqh[1][st], acc1, 0, 0, 0);
                acc1 = __builtin_amdgcn_mfma_f32_16x16x32_f16(kah, bql[1][st], acc1, 0, 0, 0);
            }
            __builtin_amdgcn_s_setprio(0);
            const int kb2 = kbase + kt * 16 + 4 * g;
            float4 w0[4], w1[4];
#pragma unroll
            for (int r = 0; r < 4; ++r) {
                w0[r] = *(const float4*)&vo[(kb2 + r) * 8];
                w1[r] = *(const float4*)&vo[(kb2 + r) * 8 + 4];
            }
#pragma unroll
            for (int rs = 0; rs < 2; ++rs) {
                f32x4 s = rs ? acc1 : acc0;
                float cm = fmaxf(fmaxf(s[0], s[1]), fmaxf(s[2], s[3]));
                float mn = fmaxf(m_[rs], cm);
                float rsc = __expf(m_[rs] - mn);
                float p0 = __expf(s[0] - mn);
                float p1 = __expf(s[1] - mn);
                float p2 = __expf(s[2] - mn);
                float p3 = __expf(s[3] - mn);
                l_[rs] = l_[rs] * rsc + (p0 + p1 + p2 + p3);
                m_[rs] = mn;
                pv[rs][0] = pv[rs][0]*rsc + p0*w0[0].x + p1*w0[1].x + p2*w0[2].x + p3*w0[3].x;
                pv[rs][1] = pv[rs][1]*rsc + p0*w0[0].y + p1*w0[1].y + p2*w0[2].y + p3*w0[3].y;
                pv[rs][2] = pv[rs][2]*rsc + p0*w0[0].z + p1*w0[1].z + p2*w0[2].z + p3*w0[3].z;
                pv[rs][3] = pv[rs][3]*rsc + p0*w0[0].w + p1*w0[1].w + p2*w0[2].w + p3*w0[3].w;
                pv[rs][4] = pv[rs][4]*rsc + p0*w1[0].x + p1*w1[1].x + p2*w1[2].x + p3*w1[3].x;
                pv[rs][5] = pv[rs][5]*rsc + p0*w1[0].y + p1*w1[1].y + p2*w1[2].y + p3*w1[3].y;
                pv[rs][6] = pv[rs][6]*rsc + p0*w1[0].z + p1*w1[1].z + p2*w1[2].z + p3*w1[3].z;
                pv[rs][7] = pv[rs][7]*rsc + p0*w1[0].w + p1*w1[1].w + p2*w1[2].w + p3*w1[3].w;
            }
        }
        __syncthreads();
        cur ^= 1;
    }
    // --- merge across the 4 lanes (g=0..3) sharing each q-row ---
#pragma unroll
    for (int msk = 16; msk <= 32; msk <<= 1) {
#pragma unroll
        for (int rs = 0; rs < 2; ++rs) {
            float mo = __shfl_xor(m_[rs], msk);
            float lo = __shfl_xor(l_[rs], msk);
            float mn = fmaxf(m_[rs], mo);
            float a = __expf(m_[rs] - mn), b = __expf(mo - mn);
            l_[rs] = l_[rs] * a + lo * b;
#pragma unroll
            for (int e = 0; e < 8; ++e) {
                float po = __shfl_xor(pv[rs][e], msk);
                pv[rs][e] = pv[rs][e] * a + po * b;
            }
            m_[rs] = mn;
        }
    }
    if (g == 0) {
#pragma unroll
        for (int rs = 0; rs < 2; ++rs) {
            int n = n0 + w * 32 + rs * 16 + c;
            pm[split * NN + n] = m_[rs];
            pl[split * NN + n] = l_[rs];
#pragma unroll
            for (int e = 0; e < 8; ++e)
                pacc[(size_t)split * NN * 8 + n * 8 + e] = pv[rs][e];
        }
    }
}

// ----------------------------------- merge split-K partials -> top2 weights
__global__ __launch_bounds__(256) void k_attn_merge(
    const float* __restrict__ pm, const float* __restrict__ pl,
    const float* __restrict__ pacc, const float* __restrict__ outb,
    float* __restrict__ sparse, int* __restrict__ i1o)
{
    int n = blockIdx.x * 256 + threadIdx.x;
    float mn = -INFINITY;
#pragma unroll
    for (int s = 0; s < ASPLIT; ++s) mn = fmaxf(mn, pm[s * NN + n]);
    float l = 0.f;
    float lg[8];
#pragma unroll
    for (int e = 0; e < 8; ++e) lg[e] = 0.f;
#pragma unroll
    for (int s = 0; s < ASPLIT; ++s) {
        float r = __expf(pm[s * NN + n] - mn);
        l += pl[s * NN + n] * r;
#pragma unroll
        for (int e = 0; e < 8; ++e)
            lg[e] += pacc[(size_t)s * NN * 8 + n * 8 + e] * r;
    }
    float inv = 1.f / l;
#pragma unroll
    for (int e = 0; e < 8; ++e) lg[e] = lg[e] * inv + outb[e];
    int i1 = 0; float v1 = lg[0];
#pragma unroll
    for (int e = 1; e < 8; ++e) if (lg[e] > v1) { v1 = lg[e]; i1 = e; }
    int i2 = -1; float v2 = -INFINITY;
#pragma unroll
    for (int e = 0; e < 8; ++e) if (e != i1 && lg[e] > v2) { v2 = lg[e]; i2 = e; }
    float e2 = __expf(v2 - v1);
    float w1 = 1.f / (1.f + e2);
    float w2 = e2 / (1.f + e2);
#pragma unroll
    for (int e = 0; e < 8; ++e)
        sparse[n * 8 + e] = (e == i1) ? w1 : ((e == i2) ? w2 : 0.f);
    i1o[n] = i1;
}

// ------------------- bf16 gather-mean: X = bf16(src + neigh_mean(src))
// 1-D grid: expert = bid & ((1<<eshift)-1) (XCD-pinned), node-blk = bid>>eshift
// 4-way unrolled gather: 4 row-loads in flight, 4 independent accumulators.
__global__ __launch_bounds__(256) void k_agg_b2b(
    const unsigned short* __restrict__ HeAll, const int* __restrict__ rowptr,
    const int* __restrict__ colidx, unsigned short* __restrict__ XAll,
    int eshift)
{
    const int bid = blockIdx.x;
    const int e = bid & ((1 << eshift) - 1);
    const int nb = bid >> eshift;
    const unsigned short* He = HeAll + (size_t)e * NN * 256;
    unsigned short* X = XAll + (size_t)e * NN * 256;
    int n = nb * 4 + (threadIdx.x >> 6);
    int c4 = (threadIdx.x & 63) * 4;
    int r0 = rowptr[n], r1 = rowptr[n + 1];
    float a0 = 0.f, a1 = 0.f, a2 = 0.f, a3 = 0.f;
    float b0 = 0.f, b1 = 0.f, b2 = 0.f, b3 = 0.f;
    float e0 = 0.f, e1 = 0.f, e2 = 0.f, e3 = 0.f;
    float d0 = 0.f, d1 = 0.f, d2 = 0.f, d3 = 0.f;
    int i = r0;
    for (; i + 4 <= r1; i += 4) {
        int s0 = colidx[i], s1 = colidx[i + 1], s2 = colidx[i + 2], s3 = colidx[i + 3];
        ushort4 v0 = *(const ushort4*)&He[(size_t)s0 * 256 + c4];
        ushort4 v1 = *(const ushort4*)&He[(size_t)s1 * 256 + c4];
        ushort4 v2 = *(const ushort4*)&He[(size_t)s2 * 256 + c4];
        ushort4 v3 = *(const ushort4*)&He[(size_t)s3 * 256 + c4];
        a0 += b2f(v0.x); a1 += b2f(v0.y); a2 += b2f(v0.z); a3 += b2f(v0.w);
        b0 += b2f(v1.x); b1 += b2f(v1.y); b2 += b2f(v1.z); b3 += b2f(v1.w);
        e0 += b2f(v2.x); e1 += b2f(v2.y); e2 += b2f(v2.z); e3 += b2f(v2.w);
        d0 += b2f(v3.x); d1 += b2f(v3.y); d2 += b2f(v3.z); d3 += b2f(v3.w);
    }
    for (; i < r1; ++i) {
        int sn = colidx[i];
        ushort4 v = *(const ushort4*)&He[(size_t)sn * 256 + c4];
        a0 += b2f(v.x); a1 += b2f(v.y); a2 += b2f(v.z); a3 += b2f(v.w);
    }
    a0 += b0 + e0 + d0; a1 += b1 + e1 + d1;
    a2 += b2 + e2 + d2; a3 += b3 + e3 + d3;
    int deg = r1 - r0;
    float inv = 1.f / (float)(deg > 1 ? deg : 1);
    ushort4 self = *(const ushort4*)&He[(size_t)n * 256 + c4];
    ushort4 o;
    o.x = f2bf(b2f(self.x) + a0 * inv); o.y = f2bf(b2f(self.y) + a1 * inv);
    o.z = f2bf(b2f(self.z) + a2 * inv); o.w = f2bf(b2f(self.w) + a3 * inv);
    *(ushort4*)&X[(size_t)n * 256 + c4] = o;
}

// ------------------------------------------------ out = Ys[0] + Ys[1]
__global__ __launch_bounds__(256) void k_combine2(const float* __restrict__ Ys,
                                                  float* __restrict__ out)
{
    int i = (blockIdx.x * 256 + threadIdx.x) * 4;
    float4 a = *(const float4*)&Ys[i];
    float4 b = *(const float4*)&Ys[(size_t)NN * 256 + i];
    float4 o;
    o.x = a.x + b.x; o.y = a.y + b.y; o.z = a.z + b.z; o.w = a.w + b.w;
    *(float4*)&out[i] = o;
}

// ==========================================================================
extern "C" void kernel_launch(void* const* d_in, const int* in_sizes, int n_in,
                              void* d_out, int out_size, void* d_ws, size_t ws_size,
                              hipStream_t stream)
{
    (void)n_in; (void)out_size;
    const float* x     = (const float*)d_in[0];
    const int*   ei    = (const int*)d_in[1];
    const int*   batch = (const int*)d_in[2];
    const float* encW  = (const float*)d_in[3];
    const float* encb  = (const float*)d_in[4];
    const float* qW    = (const float*)d_in[5];
    const float* qb    = (const float*)d_in[6];
    const float* kW    = (const float*)d_in[7];
    const float* kb    = (const float*)d_in[8];
    const float* vW    = (const float*)d_in[9];
    const float* vb    = (const float*)d_in[10];
    const float* outW  = (const float*)d_in[11];
    const float* outb  = (const float*)d_in[12];
    const float* eWh   = (const float*)d_in[13];
    const float* ebh   = (const float*)d_in[14];
    const float* eWo   = (const float*)d_in[15];
    const float* ebo   = (const float*)d_in[16];
    float* out = (float*)d_out;
    if (in_sizes[0] != NN * 6 || in_sizes[1] != 2 * NE) return;

    char* wsp = (char*)d_ws;
    size_t off = 0;
    auto alloc = [&](size_t bytes) -> void* {
        void* p = wsp + off;
        off += (bytes + 511) & ~(size_t)511;
        return p;
    };
    _Float16* zh = (_Float16*)alloc((size_t)NN * ZK * 2);
    _Float16* zl = (_Float16*)alloc((size_t)NN * ZK * 2);
    unsigned short* zb = (unsigned short*)alloc((size_t)NN * 256 * 2);
    // 16MB block: q/k split-fp16; reused as Ys (2 x NN x 256 fp32) after attn
    _Float16* qh = (_Float16*)alloc((size_t)4 * NN * 256 * 2);
    _Float16* ql = qh + (size_t)NN * 256;
    _Float16* kh = ql + (size_t)NN * 256;
    _Float16* kl = kh + (size_t)NN * 256;
    float* Ys = (float*)qh;
    float* vo     = (float*)alloc((size_t)NN * 8 * 4);
    float* sparse = (float*)alloc((size_t)NN * 8 * 4);
    int*   i1buf  = (int*)alloc((size_t)NN * 4);
    unsigned short* Xball = (unsigned short*)alloc((size_t)8 * NN * 256 * 2);
    unsigned short* Heb   = (unsigned short*)alloc((size_t)8 * NN * 256 * 2);
    unsigned short* Bth   = (unsigned short*)alloc((size_t)16 * 65536 * 2);
    unsigned short* Bto   = (unsigned short*)alloc((size_t)8 * 65536 * 2);
    _Float16* Wth = (_Float16*)alloc((size_t)2 * 256 * ZK * 2);
    _Float16* Wtl = (_Float16*)alloc((size_t)2 * 256 * ZK * 2);
    float* Wvo  = (float*)alloc((size_t)ZK * 8 * 4);
    float* bvo  = (float*)alloc(8 * 4);
    float* pm   = (float*)alloc((size_t)ASPLIT * NN * 4);
    float* plb  = (float*)alloc((size_t)ASPLIT * NN * 4);
    float* pacc = (float*)alloc((size_t)ASPLIT * NN * 8 * 4);
    int* ints   = (int*)alloc((size_t)(NG + NG + NN + NN) * 4);
    int* ncnt = ints, *ecnt = ints + NG, *indeg = ecnt + NG, *cursor = indeg + NN;
    int* rowptr = (int*)alloc((size_t)(NN + 1) * 4);
    int* colidx = (int*)alloc((size_t)NE * 4);
    if (off > ws_size) return;

    hipMemsetAsync(ints, 0, (size_t)(NG + NG + NN + NN) * 4, stream);
    k_counts<<<64, 256, 0, stream>>>(ei, batch, ncnt, ecnt, indeg);
    k_prep_qkw<<<(2 * 256 * ZK) / 256, 256, 0, stream>>>(qW, kW, Wth, Wtl);
    k_prep_vo<<<(ZK * 8 + 8 + 255) / 256, 256, 0, stream>>>(vW, vb, outW, Wvo, bvo);
    k_prep_w<<<(24 * 65536) / 256, 256, 0, stream>>>(eWh, eWo, Bth, Bto);
    k_encoder<<<NN, 256, 0, stream>>>(x, encW, encb, batch, ncnt, ecnt, zh, zl, zb);
    k_scan<<<1, 256, 0, stream>>>(indeg, rowptr);
    k_fill<<<(NE + 255) / 256, 256, 0, stream>>>(ei, rowptr, cursor, colidx);

    float scale = 1.f / sqrtf(258.f);
    k_gemm_qk<<<256, 512, 0, stream>>>(zh, zl, Wth, Wtl, qb, kb,
                                       qh, ql, kh, kl, scale);
    k_vo<<<NN / 4, 256, 0, stream>>>(zh, zl, Wvo, bvo, vo);

    k_attn_mfma<<<(NN / QB) * ASPLIT, 512, 0, stream>>>(qh, ql, kh, kl, vo, pm, plb, pacc);
    k_attn_merge<<<NN / 256, 256, 0, stream>>>(pm, plb, pacc, outb, sparse, i1buf);

    // ---- experts: 3 batched agg + 3 batched MFMA GEMMs + combine ----
    k_agg_b2b<<<NN / 4, 256, 0, stream>>>(zb, rowptr, colidx, Xball, 0);  // slot 0
    // layer 1: shared A (Xball slot 0)
    k_gemm_bf<<<1024, 512, 0, stream>>>(Xball, Bth, ebh, Heb, nullptr, nullptr, nullptr,
                                        0, (long long)2 * 65536, (long long)NN * 256,
                                        2 * 256, 0);
    // layer 2
    k_agg_b2b<<<(NN / 4) * 8, 256, 0, stream>>>(Heb, rowptr, colidx, Xball, 3);
    k_gemm_bf<<<1024, 512, 0, stream>>>(Xball, Bth + 65536, ebh + 256, Heb,
                                        nullptr, nullptr, nullptr,
                                        (long long)NN * 256, (long long)2 * 65536,
                                        (long long)NN * 256, 2 * 256, 0);
    // layer 3 -> top-2 slot buffers
    k_agg_b2b<<<(NN / 4) * 8, 256, 0, stream>>>(Heb, rowptr, colidx, Xball, 3);
    k_gemm_bf<<<1024, 512, 0, stream>>>(Xball, Bto, ebo, nullptr, Ys, sparse, i1buf,
                                        (long long)NN * 256, (long long)65536,
                                        0, 256, 1);
    k_combine2<<<(NN * 256 / 4) / 256, 256, 0, stream>>>(Ys, out);
}